// Round 1
// baseline (3929.664 us; speedup 1.0000x reference)
//
#include <hip/hip_runtime.h>
#include <math.h>

// Problem constants
#define BB 512
#define SS 64
#define DD 128
#define FF 256   // 2D
#define NSYM 128
#define STK 16
#define NDEPTH 8

// Workspace offsets (in floats)
#define Z_OFF      0ull                    // B*S*F      = 8388608
#define QKV_OFF    8388608ull              // B*S*768    = 25165824
#define MEM_OFF    33554432ull             // B*16*F     = 2097152
#define MEMQKV_OFF 35651584ull             // B*16*768   = 6291456
#define PTR_OFF    41943040ull             // B*16       = 8192
#define ZF1_OFF    41951232ull             // B*256      = 131072
#define ZF2_OFF    42082304ull             // B*256      = 131072
#define READ_OFF   42213376ull             // B*256      = 131072
#define PROBS_OFF  42344448ull             // B*128      = 65536
#define QUANT_OFF  42409984ull             // B*256      = 131072
#define HALT_OFF   42541056ull             // B          = 512
#define PVAL_OFF   42541568ull             // B          = 512
#define WACT_OFF   42542080ull             // B          = 512
#define MAGP_OFF   42542592ull             // B*2        = 1024
#define WQKV_OFF   42543616ull             // 256*768    = 196608
#define MQKV_OFF   42740224ull             // 256*768    = 196608
#define CB2_OFF    42936832ull             // 128
// total = 42936960 floats = ~171.7 MB

// ---------------------------------------------------------------------------
// Build combined real weight matrix W[256][768] from complex (wr,wi)[3][128][128]
// out[c] for c<128 = real part of head-h projection, c>=128 imag part.
// qr[j] = sum_d zr[d]*Wr[j][d] - zi[d]*Wi[j][d];  qi[j] = zr*Wi + zi*Wr
__global__ void k_buildw(const float* __restrict__ wr, const float* __restrict__ wi,
                         float* __restrict__ W) {
    int idx = blockIdx.x * 256 + threadIdx.x;   // 196608 total, grid=768
    if (idx >= 256 * 768) return;
    int e  = idx / 768;
    int hc = idx % 768;
    int h  = hc >> 8;
    int c  = hc & 255;
    const float* Wr = wr + h * DD * DD;
    const float* Wi = wi + h * DD * DD;
    float v;
    if (c < DD) {
        v = (e < DD) ? Wr[c * DD + e] : -Wi[c * DD + (e - DD)];
    } else {
        int j = c - DD;
        v = (e < DD) ? Wi[j * DD + e] : Wr[j * DD + (e - DD)];
    }
    W[idx] = v;
}

__global__ void k_cb2(const float* __restrict__ cb, float* __restrict__ cb2) {
    int n = threadIdx.x;   // 128 threads
    float s = 0.f;
    for (int c = 0; c < FF; ++c) { float v = cb[n * FF + c]; s += v * v; }
    cb2[n] = s;
}

__global__ __launch_bounds__(256) void k_init(const float* __restrict__ zr_in,
                                              const float* __restrict__ zi_in,
                                              float* __restrict__ z, float* __restrict__ memv,
                                              float* __restrict__ ptrv, float* __restrict__ probs,
                                              float* __restrict__ halt, float* __restrict__ acc) {
    size_t idx = (size_t)blockIdx.x * 256 + threadIdx.x;  // grid 32768 -> 8388608
    int c = (int)(idx & 255);
    size_t bs = idx >> 8;
    z[idx] = (c < DD) ? zr_in[bs * DD + c] : zi_in[bs * DD + (c - DD)];
    acc[idx] = 0.f;
    if (idx < 2097152) memv[idx] = 0.f;
    if (idx < 8192)  ptrv[idx] = ((idx & 15) == 0) ? 1.f : 0.f;
    if (idx < 65536) probs[idx] = 0.f;
    if (idx < 512)   halt[idx] = 0.f;
}

// ---------------------------------------------------------------------------
// fp32 GEMM: C[M][768] = A[M][256] @ W[256][768].  BM=BN=128, BK=16,
// 256 threads, 8x8 scattered per-thread tile. Grid = (M/128)*6.
__global__ __launch_bounds__(256) void gemm_f32(const float* __restrict__ A,
                                                const float* __restrict__ W,
                                                float* __restrict__ C) {
    __shared__ float As[16][132];
    __shared__ float Bs[16][132];
    int bm = blockIdx.x / 6;
    int bn = blockIdx.x % 6;
    int tid = threadIdx.x;
    int tx = tid & 15, ty = tid >> 4;
    float acc[8][8];
#pragma unroll
    for (int i = 0; i < 8; ++i)
#pragma unroll
        for (int j = 0; j < 8; ++j) acc[i][j] = 0.f;

    const float* Ablk = A + (size_t)bm * 128 * 256;
    const float* Wblk = W + bn * 128;

    for (int k0 = 0; k0 < 256; k0 += 16) {
        {   // A tile 128x16
            int k = tid & 15;
            int m0 = tid >> 4;
#pragma unroll
            for (int q = 0; q < 8; ++q) {
                int m = m0 + 16 * q;
                As[k][m] = Ablk[(size_t)m * 256 + k0 + k];
            }
        }
        {   // B tile 16x128
            int n = tid & 127;
            int kb = tid >> 7;   // 0..1
#pragma unroll
            for (int q = 0; q < 8; ++q) {
                int k = kb + 2 * q;
                Bs[k][n] = Wblk[(size_t)(k0 + k) * 768 + n];
            }
        }
        __syncthreads();
#pragma unroll
        for (int k = 0; k < 16; ++k) {
            float a[8], b[8];
#pragma unroll
            for (int i = 0; i < 8; ++i) a[i] = As[k][ty + 16 * i];
#pragma unroll
            for (int j = 0; j < 8; ++j) b[j] = Bs[k][tx + 16 * j];
#pragma unroll
            for (int i = 0; i < 8; ++i)
#pragma unroll
                for (int j = 0; j < 8; ++j) acc[i][j] += a[i] * b[j];
        }
        __syncthreads();
    }
    float* Cblk = C + (size_t)bm * 128 * 768 + bn * 128;
#pragma unroll
    for (int i = 0; i < 8; ++i) {
        int m = ty + 16 * i;
#pragma unroll
        for (int j = 0; j < 8; ++j)
            Cblk[(size_t)m * 768 + tx + 16 * j] = acc[i][j];
    }
}

// ---------------------------------------------------------------------------
// Per-batch self-attention + residual + zf1 (mean).  1 block/batch, 256 thr.
__global__ __launch_bounds__(256) void k_attn(const float* __restrict__ qkv,
                                              float* __restrict__ z,
                                              float* __restrict__ zf1) {
    __shared__ float kf[64][257];
    __shared__ float vf[64][257];
    __shared__ float qrow[4][260];
    __shared__ float zfacc[4][256];
    int b = blockIdx.x;
    int tid = threadIdx.x;
    const float* qkvb = qkv + (size_t)b * SS * 768;

    for (int idx = tid; idx < 64 * 256; idx += 256) {
        int t = idx >> 8, c = idx & 255;
        kf[t][c] = qkvb[t * 768 + 256 + c];
        vf[t][c] = qkvb[t * 768 + 512 + c];
    }
    __syncthreads();

    int w = tid >> 6;
    int lane = tid & 63;
    const float scale = 0.08838834764831845f;   // 128^-0.5
    float zfl[4] = {0.f, 0.f, 0.f, 0.f};

    for (int ii = 0; ii < 16; ++ii) {
        int i = w * 16 + ii;
#pragma unroll
        for (int q = 0; q < 4; ++q)
            qrow[w][lane + 64 * q] = qkvb[i * 768 + lane + 64 * q];
        __syncthreads();
        // scores: lane = key index j
        float s = 0.f;
#pragma unroll 8
        for (int c = 0; c < 256; ++c) s += qrow[w][c] * kf[lane][c];
        s *= scale;
        // wave softmax over 64 lanes
        float m = s;
#pragma unroll
        for (int off = 1; off < 64; off <<= 1) m = fmaxf(m, __shfl_xor(m, off));
        float e = expf(s - m);
        float sum = e;
#pragma unroll
        for (int off = 1; off < 64; off <<= 1) sum += __shfl_xor(sum, off);
        float p = e / sum;
        // PV
        float out[4] = {0.f, 0.f, 0.f, 0.f};
        for (int j = 0; j < 64; ++j) {
            float pj = __shfl(p, j);
#pragma unroll
            for (int q = 0; q < 4; ++q) out[q] += pj * vf[j][lane + 64 * q];
        }
        // residual + write + zf accumulation
        float* zrow = z + (size_t)b * (SS * FF) + i * FF;
#pragma unroll
        for (int q = 0; q < 4; ++q) {
            int c = lane + 64 * q;
            float nz = out[q] + 0.1f * zrow[c];
            zrow[c] = nz;
            zfl[q] += nz;
        }
        __syncthreads();
    }
#pragma unroll
    for (int q = 0; q < 4; ++q) zfacc[w][lane + 64 * q] = zfl[q];
    __syncthreads();
    int c = tid;
    zf1[b * FF + c] = (zfacc[0][c] + zfacc[1][c] + zfacc[2][c] + zfacc[3][c]) * (1.f / 64.f);
}

// ---------------------------------------------------------------------------
// Gate + pointer + memory update.  1 block/batch, 256 threads.
__global__ __launch_bounds__(256) void k_gate(const float* __restrict__ zf1,
                                              const float* __restrict__ ctrl_w,
                                              const float* __restrict__ ctrl_b,
                                              float* __restrict__ ptrv,
                                              float* __restrict__ memv) {
    __shared__ float zf[256];
    __shared__ float g[3];
    __shared__ float oldp[16];
    int b = blockIdx.x, tid = threadIdx.x;
    zf[tid] = zf1[b * FF + tid];
    if (tid < 16) oldp[tid] = ptrv[b * STK + tid];
    __syncthreads();
    int w = tid >> 6, lane = tid & 63;
    if (w < 3) {
        float s = 0.f;
#pragma unroll
        for (int q = 0; q < 4; ++q) {
            int c = lane + 64 * q;
            s += zf[c] * ctrl_w[c * 3 + w];
        }
#pragma unroll
        for (int off = 1; off < 64; off <<= 1) s += __shfl_xor(s, off);
        if (lane == 0) g[w] = 1.f / (1.f + expf(-(s + ctrl_b[w])));
    }
    __syncthreads();
    float tot = g[0] + g[1] + g[2] + 1e-6f;
    float push = g[0] / tot, pop = g[1] / tot, stay = g[2] / tot;
    if (tid < 16) {
        int s = tid;
        float np = push * oldp[(s + 15) & 15] + pop * oldp[(s + 1) & 15] + stay * oldp[s];
        ptrv[b * STK + s] = np;
    }
    for (int idx = tid; idx < STK * FF; idx += 256) {
        int c = idx & 255;
        size_t gi = (size_t)b * (STK * FF) + idx;
        float m = memv[gi];
        memv[gi] = m * (1.f - push) + push * zf[c];
    }
}

// ---------------------------------------------------------------------------
// Memory attention + pointer-weighted read.  1 block/batch, 256 threads.
__global__ __launch_bounds__(256) void k_memattn(const float* __restrict__ memqkv,
                                                 const float* __restrict__ ptrv,
                                                 float* __restrict__ readv) {
    __shared__ float mq[16][257];
    __shared__ float mk[16][257];
    __shared__ float mv[16][257];
    __shared__ float sm[16][17];
    __shared__ float rowmax[16], rowsum[16], pw[16];
    int b = blockIdx.x, tid = threadIdx.x;
    const float* mb = memqkv + (size_t)b * STK * 768;
    for (int idx = tid; idx < STK * FF; idx += 256) {
        int t = idx >> 8, c = idx & 255;
        mq[t][c] = mb[t * 768 + c];
        mk[t][c] = mb[t * 768 + 256 + c];
        mv[t][c] = mb[t * 768 + 512 + c];
    }
    __syncthreads();
    int i = tid >> 4, j = tid & 15;
    float s = 0.f;
#pragma unroll 8
    for (int c = 0; c < 256; ++c) s += mq[i][c] * mk[j][c];
    s *= 0.08838834764831845f;
    sm[i][j] = s;
    __syncthreads();
    if (tid < 16) {
        float m = -1e30f;
        for (int jj = 0; jj < 16; ++jj) m = fmaxf(m, sm[tid][jj]);
        float su = 0.f;
        for (int jj = 0; jj < 16; ++jj) su += expf(sm[tid][jj] - m);
        rowmax[tid] = m; rowsum[tid] = su;
    }
    __syncthreads();
    float p = expf(s - rowmax[i]) / rowsum[i];
    sm[i][j] = p;
    __syncthreads();
    if (tid < 16) {
        float a = 0.f;
        for (int ss2 = 0; ss2 < 16; ++ss2) a += ptrv[b * STK + ss2] * sm[ss2][tid];
        pw[tid] = a;
    }
    __syncthreads();
    {
        int c = tid;   // 0..255
        float a = 0.f;
#pragma unroll
        for (int jj = 0; jj < 16; ++jj) a += pw[jj] * mv[jj][c];
        readv[b * FF + c] = a;
    }
}

// ---------------------------------------------------------------------------
__device__ __forceinline__ float bredsum(float v, float* red, int n) {
    red[n] = v; __syncthreads();
    for (int off = 64; off > 0; off >>= 1) {
        if (n < off) red[n] += red[n + off];
        __syncthreads();
    }
    float r = red[0];
    __syncthreads();
    return r;
}
__device__ __forceinline__ float bredmax(float v, float* red, int n) {
    red[n] = v; __syncthreads();
    for (int off = 64; off > 0; off >>= 1) {
        if (n < off) red[n] = fmaxf(red[n], red[n + off]);
        __syncthreads();
    }
    float r = red[0];
    __syncthreads();
    return r;
}

// z += 0.1*read; zf2 = mean; mag partial sums; halting logit. 1 blk/batch, 128 thr.
__global__ __launch_bounds__(128) void k_zup2(float* __restrict__ z,
                                              const float* __restrict__ readv,
                                              float* __restrict__ zf2,
                                              const float* __restrict__ halt_w,
                                              const float* __restrict__ halt_b,
                                              float* __restrict__ pval,
                                              float* __restrict__ magpart) {
    __shared__ float red[128];
    int b = blockIdx.x, d = threadIdx.x;
    float rr = 0.1f * readv[b * FF + d];
    float ri = 0.1f * readv[b * FF + DD + d];
    float sr = 0.f, si = 0.f, ms = 0.f, msq = 0.f;
    float* zb = z + (size_t)b * (SS * FF);
    for (int s = 0; s < SS; ++s) {
        float zr = zb[s * FF + d] + rr;
        float zi = zb[s * FF + DD + d] + ri;
        zb[s * FF + d] = zr;
        zb[s * FF + DD + d] = zi;
        sr += zr; si += zi;
        float m2 = zr * zr + zi * zi;
        ms += sqrtf(m2); msq += m2;
    }
    float zfr = sr * (1.f / 64.f), zfi = si * (1.f / 64.f);
    zf2[b * FF + d] = zfr;
    zf2[b * FF + DD + d] = zfi;
    float tms = bredsum(ms, red, d);
    float tmsq = bredsum(msq, red, d);
    if (d == 0) { magpart[2 * b] = tms; magpart[2 * b + 1] = tmsq; }
    float hp = zfr * halt_w[d] + zfi * halt_w[DD + d];
    float thp = bredsum(hp, red, d);
    if (d == 0) pval[b] = 1.f / (1.f + expf(-(thp + halt_b[0])));
}

// VQ + ACT bookkeeping. 1 block/batch, 128 threads (one per symbol).
__global__ __launch_bounds__(128) void k_vq(const float* __restrict__ zf2,
                                            const float* __restrict__ cb,
                                            const float* __restrict__ cb2,
                                            const float* __restrict__ adj,
                                            float* __restrict__ probs,
                                            float* __restrict__ quant,
                                            float* __restrict__ halt,
                                            const float* __restrict__ pval,
                                            float* __restrict__ wact,
                                            const float* __restrict__ magpart, int t) {
    __shared__ float red[128];
    __shared__ float zf[256];
    __shared__ float pr[128];
    int b = blockIdx.x, n = threadIdx.x;
    zf[n] = zf2[b * FF + n];
    zf[DD + n] = zf2[b * FF + DD + n];
    float up = 0.f;
    if (t > 0) {
        float pa = 0.f, pb = 0.f;
        for (int k = n; k < BB; k += 128) { pa += magpart[2 * k]; pb += magpart[2 * k + 1]; }
        float tms = bredsum(pa, red, n);
        float tmsq = bredsum(pb, red, n);
        const float N = 4194304.f;   // B*S*D
        float mean = tms / N;
        float var = tmsq / N - mean * mean;
        float x = var / (1.f + 1e-6f);
        up = (x > 20.f) ? x : log1pf(expf(x));
    }
    __syncthreads();
    float part = zf[n] * zf[n] + zf[DD + n] * zf[DD + n];
    float zz = bredsum(part, red, n);
    float dot = 0.f;
    const float* cbn = cb + n * FF;
#pragma unroll 8
    for (int c = 0; c < FF; ++c) dot += zf[c] * cbn[c];
    float dist = (zz + cb2[n] - 2.f * dot) * (1.f / 256.f);
    float dtot = dist;
    if (t > 0) {
        float gb = 0.f;
        const float* pp = probs + b * NSYM;
        for (int k = 0; k < NSYM; ++k) gb += pp[k] * adj[k * NSYM + n];
        dtot = dist - 0.01f * up * (1.f / (1.f + expf(-gb)));
    }
    float v = -dtot;   // TEMP = 1
    float mx = bredmax(v, red, n);
    float e = expf(v - mx);
    float se = bredsum(e, red, n);
    float psm = e / se;
    pr[n] = psm;
    __syncthreads();
    probs[b * NSYM + n] = psm;
    float q0 = 0.f, q1 = 0.f;
    for (int k = 0; k < NSYM; ++k) {
        float pk = pr[k];
        q0 += pk * cb[k * FF + n];
        q1 += pk * cb[k * FF + DD + n];
    }
    quant[b * FF + n] = q0;
    quant[b * FF + DD + n] = q1;
    if (n == 0) {
        float h = halt[b], p = pval[b];
        float running = (h < 0.99f) ? 1.f : 0.f;
        float w = (((h + p * running) >= 0.99f) ? (1.f - h) : p) * running;
        halt[b] = h + w;
        wact[b] = w;
    }
}

// z += 0.1*quant (broadcast over S); acc += w*z
__global__ __launch_bounds__(256) void k_final(float* __restrict__ z,
                                               const float* __restrict__ quant,
                                               const float* __restrict__ wact,
                                               float* __restrict__ acc) {
    int idx = blockIdx.x * 256 + threadIdx.x;   // grid 32768 -> 8388608
    int b = idx >> 14;     // /(S*F)
    int c = idx & 255;
    float zv = z[idx] + 0.1f * quant[b * FF + c];
    z[idx] = zv;
    acc[idx] += wact[b] * zv;
}

// ---------------------------------------------------------------------------
extern "C" void kernel_launch(void* const* d_in, const int* in_sizes, int n_in,
                              void* d_out, int out_size, void* d_ws, size_t ws_size,
                              hipStream_t stream) {
    const float* z_real  = (const float*)d_in[0];
    const float* z_imag  = (const float*)d_in[1];
    const float* attn_wr = (const float*)d_in[2];
    const float* attn_wi = (const float*)d_in[3];
    const float* mem_wr  = (const float*)d_in[4];
    const float* mem_wi  = (const float*)d_in[5];
    const float* ctrl_w  = (const float*)d_in[6];
    const float* ctrl_b  = (const float*)d_in[7];
    const float* halt_w  = (const float*)d_in[8];
    const float* halt_b  = (const float*)d_in[9];
    const float* codebook  = (const float*)d_in[10];
    const float* adjacency = (const float*)d_in[11];

    float* ws = (float*)d_ws;
    float* z      = ws + Z_OFF;
    float* qkv    = ws + QKV_OFF;
    float* memv   = ws + MEM_OFF;
    float* memqkv = ws + MEMQKV_OFF;
    float* ptrv   = ws + PTR_OFF;
    float* zf1    = ws + ZF1_OFF;
    float* zf2    = ws + ZF2_OFF;
    float* readv  = ws + READ_OFF;
    float* probs  = ws + PROBS_OFF;
    float* quant  = ws + QUANT_OFF;
    float* halt   = ws + HALT_OFF;
    float* pval   = ws + PVAL_OFF;
    float* wact   = ws + WACT_OFF;
    float* magp   = ws + MAGP_OFF;
    float* WQKV   = ws + WQKV_OFF;
    float* MQKV   = ws + MQKV_OFF;
    float* cb2    = ws + CB2_OFF;
    float* acc    = (float*)d_out;

    k_buildw<<<768, 256, 0, stream>>>(attn_wr, attn_wi, WQKV);
    k_buildw<<<768, 256, 0, stream>>>(mem_wr, mem_wi, MQKV);
    k_cb2<<<1, 128, 0, stream>>>(codebook, cb2);
    k_init<<<32768, 256, 0, stream>>>(z_real, z_imag, z, memv, ptrv, probs, halt, acc);

    for (int t = 0; t < NDEPTH; ++t) {
        gemm_f32<<<(BB * SS / 128) * 6, 256, 0, stream>>>(z, WQKV, qkv);            // 1536 blocks
        k_attn<<<BB, 256, 0, stream>>>(qkv, z, zf1);
        k_gate<<<BB, 256, 0, stream>>>(zf1, ctrl_w, ctrl_b, ptrv, memv);
        gemm_f32<<<(BB * STK / 128) * 6, 256, 0, stream>>>(memv, MQKV, memqkv);     // 384 blocks
        k_memattn<<<BB, 256, 0, stream>>>(memqkv, ptrv, readv);
        k_zup2<<<BB, 128, 0, stream>>>(z, readv, zf2, halt_w, halt_b, pval, magp);
        k_vq<<<BB, 128, 0, stream>>>(zf2, codebook, cb2, adjacency, probs, quant,
                                     halt, pval, wact, magp, t);
        k_final<<<32768, 256, 0, stream>>>(z, quant, wact, acc);
    }
}

// Round 2
// 2822.041 us; speedup vs baseline: 1.3925x; 1.3925x over previous
//
#include <hip/hip_runtime.h>
#include <math.h>

// Problem constants
#define BB 512
#define SS 64
#define DD 128
#define FF 256   // 2D
#define NSYM 128
#define STK 16
#define NDEPTH 8

typedef _Float16 half_t;
typedef __attribute__((ext_vector_type(8))) _Float16 half8;
typedef __attribute__((ext_vector_type(4))) float f32x4;

// Workspace offsets (in floats)
#define Z_OFF      0ull                    // B*S*F      = 8388608
#define QKV_OFF    8388608ull              // B*S*768    = 25165824
#define MEM_OFF    33554432ull             // B*16*F     = 2097152
#define MEMQKV_OFF 35651584ull             // B*16*768   = 6291456
#define PTR_OFF    41943040ull             // B*16       = 8192
#define ZF1_OFF    41951232ull             // B*256      = 131072
#define ZF2_OFF    42082304ull             // B*256      = 131072
#define READ_OFF   42213376ull             // B*256      = 131072
#define PROBS_OFF  42344448ull             // B*128      = 65536
#define QUANT_OFF  42409984ull             // B*256      = 131072
#define HALT_OFF   42541056ull             // B          = 512
#define PVAL_OFF   42541568ull             // B          = 512
#define WACT_OFF   42542080ull             // B          = 512
#define MAGP_OFF   42542592ull             // B*2        = 1024
#define WQKV_OFF   42543616ull             // 196608 floats (now: WTh+WTl fp16)
#define MQKV_OFF   42740224ull             // 196608 floats (now: MTh+MTl fp16)
#define CB2_OFF    42936832ull             // 128
// total = 42936960 floats = ~171.7 MB (same as round 1)

// ---------------------------------------------------------------------------
// Build TRANSPOSED, fp16-SPLIT weight planes from complex (wr,wi)[3][128][128].
// Logical W[e][hc] (e=k index 0..255, hc = h*256+c, h in {q,k,v}):
//   c<128:  W = (e<128) ? Wr[c][e] : -Wi[c][e-128]
//   c>=128: W = (e<128) ? Wi[c-128][e] : Wr[c-128][e-128]
// Output: WTh/WTl [col hc][k e] fp16, k-contiguous (ready for MFMA B frags).
__global__ void k_buildwt(const float* __restrict__ wr, const float* __restrict__ wi,
                          half_t* __restrict__ WTh, half_t* __restrict__ WTl) {
    int idx = blockIdx.x * 256 + threadIdx.x;   // 196608 total, grid=768
    if (idx >= 768 * 256) return;
    int col = idx >> 8;     // 0..767
    int e   = idx & 255;
    int h   = col >> 8;
    int c   = col & 255;
    const float* Wr = wr + h * DD * DD;
    const float* Wi = wi + h * DD * DD;
    float v;
    if (c < DD) {
        v = (e < DD) ? Wr[c * DD + e] : -Wi[c * DD + (e - DD)];
    } else {
        int j = c - DD;
        v = (e < DD) ? Wi[j * DD + e] : Wr[j * DD + (e - DD)];
    }
    half_t hh = (half_t)v;
    WTh[idx] = hh;
    WTl[idx] = (half_t)(v - (float)hh);
}

__global__ void k_cb2(const float* __restrict__ cb, float* __restrict__ cb2) {
    int n = threadIdx.x;   // 128 threads
    float s = 0.f;
    for (int c = 0; c < FF; ++c) { float v = cb[n * FF + c]; s += v * v; }
    cb2[n] = s;
}

__global__ __launch_bounds__(256) void k_init(const float* __restrict__ zr_in,
                                              const float* __restrict__ zi_in,
                                              float* __restrict__ z, float* __restrict__ memv,
                                              float* __restrict__ ptrv, float* __restrict__ probs,
                                              float* __restrict__ halt, float* __restrict__ acc) {
    size_t idx = (size_t)blockIdx.x * 256 + threadIdx.x;  // grid 32768 -> 8388608
    int c = (int)(idx & 255);
    size_t bs = idx >> 8;
    z[idx] = (c < DD) ? zr_in[bs * DD + c] : zi_in[bs * DD + (c - DD)];
    acc[idx] = 0.f;
    if (idx < 2097152) memv[idx] = 0.f;
    if (idx < 8192)  ptrv[idx] = ((idx & 15) == 0) ? 1.f : 0.f;
    if (idx < 65536) probs[idx] = 0.f;
    if (idx < 512)   halt[idx] = 0.f;
}

// ---------------------------------------------------------------------------
// Split-fp16 MFMA GEMM: C[M][768] = A[M][256] (fp32) @ W[256][768]
// using W pre-split into WTh/WTl fp16 [768][256] (transposed, k-contiguous).
// A is staged fp32 to LDS and split (ah+al) in-register.
// 3 MFMA terms: Ah*Bh + Ah*Bl + Al*Bh  -> ~2^-21 relative accuracy.
// BM=BN=128, BK=32, 256 threads = 4 waves in 2x2, each wave 64x64 (4x4 MFMA tiles).
__global__ __launch_bounds__(256) void gemm_split(const float* __restrict__ A,
                                                  const half_t* __restrict__ WTh,
                                                  const half_t* __restrict__ WTl,
                                                  float* __restrict__ C) {
    __shared__ float As[128][36];   // stride 144B -> <=2-way conflicts on frag reads
    int bm = blockIdx.x / 6;
    int bn = blockIdx.x % 6;
    int tid = threadIdx.x;
    int w = tid >> 6;
    int lane = tid & 63;
    int wr = w >> 1, wc = w & 1;
    int l15 = lane & 15;
    int lq  = lane >> 4;           // quarter-wave: supplies k-chunk

    f32x4 acc[4][4];
#pragma unroll
    for (int i = 0; i < 4; ++i)
#pragma unroll
        for (int j = 0; j < 4; ++j) acc[i][j] = (f32x4){0.f, 0.f, 0.f, 0.f};

    const float* Ablk = A + (size_t)bm * 128 * 256;
    int colbase = bn * 128 + wc * 64;

    int srow = tid >> 1;
    int sseg = (tid & 1) * 16;

    for (int k0 = 0; k0 < 256; k0 += 32) {
        __syncthreads();
        {   // stage A tile 128x32 fp32 (64B per thread)
            const float* src = Ablk + (size_t)srow * 256 + k0 + sseg;
            f32x4 v0 = *(const f32x4*)(src);
            f32x4 v1 = *(const f32x4*)(src + 4);
            f32x4 v2 = *(const f32x4*)(src + 8);
            f32x4 v3 = *(const f32x4*)(src + 12);
            *(f32x4*)&As[srow][sseg]      = v0;
            *(f32x4*)&As[srow][sseg + 4]  = v1;
            *(f32x4*)&As[srow][sseg + 8]  = v2;
            *(f32x4*)&As[srow][sseg + 12] = v3;
        }
        __syncthreads();

        // B fragments straight from L2-resident transposed split weights
        half8 bh[4], bl[4];
#pragma unroll
        for (int tj = 0; tj < 4; ++tj) {
            size_t off = (size_t)(colbase + tj * 16 + l15) * 256 + k0 + lq * 8;
            bh[tj] = *(const half8*)(WTh + off);
            bl[tj] = *(const half8*)(WTl + off);
        }

        // A fragments from LDS, split fp32 -> ah + al (fp16)
        half8 ah[4], al[4];
#pragma unroll
        for (int ti = 0; ti < 4; ++ti) {
            const float* ap = &As[wr * 64 + ti * 16 + l15][lq * 8];
            f32x4 a0 = *(const f32x4*)(ap);
            f32x4 a1 = *(const f32x4*)(ap + 4);
#pragma unroll
            for (int j = 0; j < 4; ++j) {
                float x = a0[j];
                half_t h = (half_t)x;
                ah[ti][j] = h;
                al[ti][j] = (half_t)(x - (float)h);
            }
#pragma unroll
            for (int j = 0; j < 4; ++j) {
                float x = a1[j];
                half_t h = (half_t)x;
                ah[ti][4 + j] = h;
                al[ti][4 + j] = (half_t)(x - (float)h);
            }
        }

#pragma unroll
        for (int ti = 0; ti < 4; ++ti)
#pragma unroll
            for (int tj = 0; tj < 4; ++tj)
                acc[ti][tj] = __builtin_amdgcn_mfma_f32_16x16x32_f16(ah[ti], bh[tj], acc[ti][tj], 0, 0, 0);
#pragma unroll
        for (int ti = 0; ti < 4; ++ti)
#pragma unroll
            for (int tj = 0; tj < 4; ++tj)
                acc[ti][tj] = __builtin_amdgcn_mfma_f32_16x16x32_f16(ah[ti], bl[tj], acc[ti][tj], 0, 0, 0);
#pragma unroll
        for (int ti = 0; ti < 4; ++ti)
#pragma unroll
            for (int tj = 0; tj < 4; ++tj)
                acc[ti][tj] = __builtin_amdgcn_mfma_f32_16x16x32_f16(al[ti], bh[tj], acc[ti][tj], 0, 0, 0);
    }

    // Epilogue: C/D layout col = lane&15, row = (lane>>4)*4 + r
    float* Cb = C + (size_t)(bm * 128 + wr * 64) * 768 + bn * 128 + wc * 64;
#pragma unroll
    for (int ti = 0; ti < 4; ++ti)
#pragma unroll
        for (int tj = 0; tj < 4; ++tj) {
            int r0 = ti * 16 + lq * 4;
            int c0 = tj * 16 + l15;
#pragma unroll
            for (int r = 0; r < 4; ++r)
                Cb[(size_t)(r0 + r) * 768 + c0] = acc[ti][tj][r];
        }
}

// ---------------------------------------------------------------------------
// Per-batch self-attention + residual + zf1 (mean).  1 block/batch, 256 thr.
__global__ __launch_bounds__(256) void k_attn(const float* __restrict__ qkv,
                                              float* __restrict__ z,
                                              float* __restrict__ zf1) {
    __shared__ float kf[64][257];
    __shared__ float vf[64][257];
    __shared__ float qrow[4][260];
    __shared__ float zfacc[4][256];
    int b = blockIdx.x;
    int tid = threadIdx.x;
    const float* qkvb = qkv + (size_t)b * SS * 768;

    for (int idx = tid; idx < 64 * 256; idx += 256) {
        int t = idx >> 8, c = idx & 255;
        kf[t][c] = qkvb[t * 768 + 256 + c];
        vf[t][c] = qkvb[t * 768 + 512 + c];
    }
    __syncthreads();

    int w = tid >> 6;
    int lane = tid & 63;
    const float scale = 0.08838834764831845f;   // 128^-0.5
    float zfl[4] = {0.f, 0.f, 0.f, 0.f};

    for (int ii = 0; ii < 16; ++ii) {
        int i = w * 16 + ii;
#pragma unroll
        for (int q = 0; q < 4; ++q)
            qrow[w][lane + 64 * q] = qkvb[i * 768 + lane + 64 * q];
        __syncthreads();
        float s = 0.f;
#pragma unroll 8
        for (int c = 0; c < 256; ++c) s += qrow[w][c] * kf[lane][c];
        s *= scale;
        float m = s;
#pragma unroll
        for (int off = 1; off < 64; off <<= 1) m = fmaxf(m, __shfl_xor(m, off));
        float e = expf(s - m);
        float sum = e;
#pragma unroll
        for (int off = 1; off < 64; off <<= 1) sum += __shfl_xor(sum, off);
        float p = e / sum;
        float out[4] = {0.f, 0.f, 0.f, 0.f};
        for (int j = 0; j < 64; ++j) {
            float pj = __shfl(p, j);
#pragma unroll
            for (int q = 0; q < 4; ++q) out[q] += pj * vf[j][lane + 64 * q];
        }
        float* zrow = z + (size_t)b * (SS * FF) + i * FF;
#pragma unroll
        for (int q = 0; q < 4; ++q) {
            int c = lane + 64 * q;
            float nz = out[q] + 0.1f * zrow[c];
            zrow[c] = nz;
            zfl[q] += nz;
        }
        __syncthreads();
    }
#pragma unroll
    for (int q = 0; q < 4; ++q) zfacc[w][lane + 64 * q] = zfl[q];
    __syncthreads();
    int c = tid;
    zf1[b * FF + c] = (zfacc[0][c] + zfacc[1][c] + zfacc[2][c] + zfacc[3][c]) * (1.f / 64.f);
}

// ---------------------------------------------------------------------------
// Gate + pointer + memory update.  1 block/batch, 256 threads.
__global__ __launch_bounds__(256) void k_gate(const float* __restrict__ zf1,
                                              const float* __restrict__ ctrl_w,
                                              const float* __restrict__ ctrl_b,
                                              float* __restrict__ ptrv,
                                              float* __restrict__ memv) {
    __shared__ float zf[256];
    __shared__ float g[3];
    __shared__ float oldp[16];
    int b = blockIdx.x, tid = threadIdx.x;
    zf[tid] = zf1[b * FF + tid];
    if (tid < 16) oldp[tid] = ptrv[b * STK + tid];
    __syncthreads();
    int w = tid >> 6, lane = tid & 63;
    if (w < 3) {
        float s = 0.f;
#pragma unroll
        for (int q = 0; q < 4; ++q) {
            int c = lane + 64 * q;
            s += zf[c] * ctrl_w[c * 3 + w];
        }
#pragma unroll
        for (int off = 1; off < 64; off <<= 1) s += __shfl_xor(s, off);
        if (lane == 0) g[w] = 1.f / (1.f + expf(-(s + ctrl_b[w])));
    }
    __syncthreads();
    float tot = g[0] + g[1] + g[2] + 1e-6f;
    float push = g[0] / tot, pop = g[1] / tot, stay = g[2] / tot;
    if (tid < 16) {
        int s = tid;
        float np = push * oldp[(s + 15) & 15] + pop * oldp[(s + 1) & 15] + stay * oldp[s];
        ptrv[b * STK + s] = np;
    }
    for (int idx = tid; idx < STK * FF; idx += 256) {
        int c = idx & 255;
        size_t gi = (size_t)b * (STK * FF) + idx;
        float m = memv[gi];
        memv[gi] = m * (1.f - push) + push * zf[c];
    }
}

// ---------------------------------------------------------------------------
// Memory attention + pointer-weighted read.  1 block/batch, 256 threads.
__global__ __launch_bounds__(256) void k_memattn(const float* __restrict__ memqkv,
                                                 const float* __restrict__ ptrv,
                                                 float* __restrict__ readv) {
    __shared__ float mq[16][257];
    __shared__ float mk[16][257];
    __shared__ float mv[16][257];
    __shared__ float sm[16][17];
    __shared__ float rowmax[16], rowsum[16], pw[16];
    int b = blockIdx.x, tid = threadIdx.x;
    const float* mb = memqkv + (size_t)b * STK * 768;
    for (int idx = tid; idx < STK * FF; idx += 256) {
        int t = idx >> 8, c = idx & 255;
        mq[t][c] = mb[t * 768 + c];
        mk[t][c] = mb[t * 768 + 256 + c];
        mv[t][c] = mb[t * 768 + 512 + c];
    }
    __syncthreads();
    int i = tid >> 4, j = tid & 15;
    float s = 0.f;
#pragma unroll 8
    for (int c = 0; c < 256; ++c) s += mq[i][c] * mk[j][c];
    s *= 0.08838834764831845f;
    sm[i][j] = s;
    __syncthreads();
    if (tid < 16) {
        float m = -1e30f;
        for (int jj = 0; jj < 16; ++jj) m = fmaxf(m, sm[tid][jj]);
        float su = 0.f;
        for (int jj = 0; jj < 16; ++jj) su += expf(sm[tid][jj] - m);
        rowmax[tid] = m; rowsum[tid] = su;
    }
    __syncthreads();
    float p = expf(s - rowmax[i]) / rowsum[i];
    sm[i][j] = p;
    __syncthreads();
    if (tid < 16) {
        float a = 0.f;
        for (int ss2 = 0; ss2 < 16; ++ss2) a += ptrv[b * STK + ss2] * sm[ss2][tid];
        pw[tid] = a;
    }
    __syncthreads();
    {
        int c = tid;
        float a = 0.f;
#pragma unroll
        for (int jj = 0; jj < 16; ++jj) a += pw[jj] * mv[jj][c];
        readv[b * FF + c] = a;
    }
}

// ---------------------------------------------------------------------------
__device__ __forceinline__ float bredsum(float v, float* red, int n) {
    red[n] = v; __syncthreads();
    for (int off = 64; off > 0; off >>= 1) {
        if (n < off) red[n] += red[n + off];
        __syncthreads();
    }
    float r = red[0];
    __syncthreads();
    return r;
}
__device__ __forceinline__ float bredmax(float v, float* red, int n) {
    red[n] = v; __syncthreads();
    for (int off = 64; off > 0; off >>= 1) {
        if (n < off) red[n] = fmaxf(red[n], red[n + off]);
        __syncthreads();
    }
    float r = red[0];
    __syncthreads();
    return r;
}

// z += 0.1*read; zf2 = mean; mag partial sums; halting logit. 1 blk/batch, 128 thr.
__global__ __launch_bounds__(128) void k_zup2(float* __restrict__ z,
                                              const float* __restrict__ readv,
                                              float* __restrict__ zf2,
                                              const float* __restrict__ halt_w,
                                              const float* __restrict__ halt_b,
                                              float* __restrict__ pval,
                                              float* __restrict__ magpart) {
    __shared__ float red[128];
    int b = blockIdx.x, d = threadIdx.x;
    float rr = 0.1f * readv[b * FF + d];
    float ri = 0.1f * readv[b * FF + DD + d];
    float sr = 0.f, si = 0.f, ms = 0.f, msq = 0.f;
    float* zb = z + (size_t)b * (SS * FF);
    for (int s = 0; s < SS; ++s) {
        float zr = zb[s * FF + d] + rr;
        float zi = zb[s * FF + DD + d] + ri;
        zb[s * FF + d] = zr;
        zb[s * FF + DD + d] = zi;
        sr += zr; si += zi;
        float m2 = zr * zr + zi * zi;
        ms += sqrtf(m2); msq += m2;
    }
    float zfr = sr * (1.f / 64.f), zfi = si * (1.f / 64.f);
    zf2[b * FF + d] = zfr;
    zf2[b * FF + DD + d] = zfi;
    float tms = bredsum(ms, red, d);
    float tmsq = bredsum(msq, red, d);
    if (d == 0) { magpart[2 * b] = tms; magpart[2 * b + 1] = tmsq; }
    float hp = zfr * halt_w[d] + zfi * halt_w[DD + d];
    float thp = bredsum(hp, red, d);
    if (d == 0) pval[b] = 1.f / (1.f + expf(-(thp + halt_b[0])));
}

// VQ + ACT bookkeeping. 1 block/batch, 128 threads (one per symbol).
__global__ __launch_bounds__(128) void k_vq(const float* __restrict__ zf2,
                                            const float* __restrict__ cb,
                                            const float* __restrict__ cb2,
                                            const float* __restrict__ adj,
                                            float* __restrict__ probs,
                                            float* __restrict__ quant,
                                            float* __restrict__ halt,
                                            const float* __restrict__ pval,
                                            float* __restrict__ wact,
                                            const float* __restrict__ magpart, int t) {
    __shared__ float red[128];
    __shared__ float zf[256];
    __shared__ float pr[128];
    int b = blockIdx.x, n = threadIdx.x;
    zf[n] = zf2[b * FF + n];
    zf[DD + n] = zf2[b * FF + DD + n];
    float up = 0.f;
    if (t > 0) {
        float pa = 0.f, pb = 0.f;
        for (int k = n; k < BB; k += 128) { pa += magpart[2 * k]; pb += magpart[2 * k + 1]; }
        float tms = bredsum(pa, red, n);
        float tmsq = bredsum(pb, red, n);
        const float N = 4194304.f;   // B*S*D
        float mean = tms / N;
        float var = tmsq / N - mean * mean;
        float x = var / (1.f + 1e-6f);
        up = (x > 20.f) ? x : log1pf(expf(x));
    }
    __syncthreads();
    float part = zf[n] * zf[n] + zf[DD + n] * zf[DD + n];
    float zz = bredsum(part, red, n);
    float dot = 0.f;
    const float* cbn = cb + n * FF;
#pragma unroll 8
    for (int c = 0; c < FF; ++c) dot += zf[c] * cbn[c];
    float dist = (zz + cb2[n] - 2.f * dot) * (1.f / 256.f);
    float dtot = dist;
    if (t > 0) {
        float gb = 0.f;
        const float* pp = probs + b * NSYM;
        for (int k = 0; k < NSYM; ++k) gb += pp[k] * adj[k * NSYM + n];
        dtot = dist - 0.01f * up * (1.f / (1.f + expf(-gb)));
    }
    float v = -dtot;   // TEMP = 1
    float mx = bredmax(v, red, n);
    float e = expf(v - mx);
    float se = bredsum(e, red, n);
    float psm = e / se;
    pr[n] = psm;
    __syncthreads();
    probs[b * NSYM + n] = psm;
    float q0 = 0.f, q1 = 0.f;
    for (int k = 0; k < NSYM; ++k) {
        float pk = pr[k];
        q0 += pk * cb[k * FF + n];
        q1 += pk * cb[k * FF + DD + n];
    }
    quant[b * FF + n] = q0;
    quant[b * FF + DD + n] = q1;
    if (n == 0) {
        float h = halt[b], p = pval[b];
        float running = (h < 0.99f) ? 1.f : 0.f;
        float w = (((h + p * running) >= 0.99f) ? (1.f - h) : p) * running;
        halt[b] = h + w;
        wact[b] = w;
    }
}

// z += 0.1*quant (broadcast over S); acc += w*z
__global__ __launch_bounds__(256) void k_final(float* __restrict__ z,
                                               const float* __restrict__ quant,
                                               const float* __restrict__ wact,
                                               float* __restrict__ acc) {
    int idx = blockIdx.x * 256 + threadIdx.x;   // grid 32768 -> 8388608
    int b = idx >> 14;     // /(S*F)
    int c = idx & 255;
    float zv = z[idx] + 0.1f * quant[b * FF + c];
    z[idx] = zv;
    acc[idx] += wact[b] * zv;
}

// ---------------------------------------------------------------------------
extern "C" void kernel_launch(void* const* d_in, const int* in_sizes, int n_in,
                              void* d_out, int out_size, void* d_ws, size_t ws_size,
                              hipStream_t stream) {
    const float* z_real  = (const float*)d_in[0];
    const float* z_imag  = (const float*)d_in[1];
    const float* attn_wr = (const float*)d_in[2];
    const float* attn_wi = (const float*)d_in[3];
    const float* mem_wr  = (const float*)d_in[4];
    const float* mem_wi  = (const float*)d_in[5];
    const float* ctrl_w  = (const float*)d_in[6];
    const float* ctrl_b  = (const float*)d_in[7];
    const float* halt_w  = (const float*)d_in[8];
    const float* halt_b  = (const float*)d_in[9];
    const float* codebook  = (const float*)d_in[10];
    const float* adjacency = (const float*)d_in[11];

    float* ws = (float*)d_ws;
    float* z      = ws + Z_OFF;
    float* qkv    = ws + QKV_OFF;
    float* memv   = ws + MEM_OFF;
    float* memqkv = ws + MEMQKV_OFF;
    float* ptrv   = ws + PTR_OFF;
    float* zf1    = ws + ZF1_OFF;
    float* zf2    = ws + ZF2_OFF;
    float* readv  = ws + READ_OFF;
    float* probs  = ws + PROBS_OFF;
    float* quant  = ws + QUANT_OFF;
    float* halt   = ws + HALT_OFF;
    float* pval   = ws + PVAL_OFF;
    float* wact   = ws + WACT_OFF;
    float* magp   = ws + MAGP_OFF;
    half_t* WTh_a = (half_t*)(ws + WQKV_OFF);
    half_t* WTl_a = (half_t*)(ws + WQKV_OFF) + 196608;
    half_t* WTh_m = (half_t*)(ws + MQKV_OFF);
    half_t* WTl_m = (half_t*)(ws + MQKV_OFF) + 196608;
    float* cb2    = ws + CB2_OFF;
    float* acc    = (float*)d_out;

    k_buildwt<<<768, 256, 0, stream>>>(attn_wr, attn_wi, WTh_a, WTl_a);
    k_buildwt<<<768, 256, 0, stream>>>(mem_wr, mem_wi, WTh_m, WTl_m);
    k_cb2<<<1, 128, 0, stream>>>(codebook, cb2);
    k_init<<<32768, 256, 0, stream>>>(z_real, z_imag, z, memv, ptrv, probs, halt, acc);

    for (int t = 0; t < NDEPTH; ++t) {
        gemm_split<<<(BB * SS / 128) * 6, 256, 0, stream>>>(z, WTh_a, WTl_a, qkv);       // 1536 blocks
        k_attn<<<BB, 256, 0, stream>>>(qkv, z, zf1);
        k_gate<<<BB, 256, 0, stream>>>(zf1, ctrl_w, ctrl_b, ptrv, memv);
        gemm_split<<<(BB * STK / 128) * 6, 256, 0, stream>>>(memv, WTh_m, WTl_m, memqkv); // 384 blocks
        k_memattn<<<BB, 256, 0, stream>>>(memqkv, ptrv, readv);
        k_zup2<<<BB, 128, 0, stream>>>(z, readv, zf2, halt_w, halt_b, pval, magp);
        k_vq<<<BB, 128, 0, stream>>>(zf2, codebook, cb2, adjacency, probs, quant,
                                     halt, pval, wact, magp, t);
        k_final<<<32768, 256, 0, stream>>>(z, quant, wact, acc);
    }
}

// Round 3
// 1697.143 us; speedup vs baseline: 2.3155x; 1.6628x over previous
//
#include <hip/hip_runtime.h>
#include <math.h>

// Problem constants
#define BB 512
#define SS 64
#define DD 128
#define FF 256   // 2D
#define NSYM 128
#define STK 16
#define NDEPTH 8

typedef _Float16 half_t;
typedef __attribute__((ext_vector_type(4))) _Float16 half4;
typedef __attribute__((ext_vector_type(8))) _Float16 half8;
typedef __attribute__((ext_vector_type(4))) float f32x4;

// Workspace offsets (in floats)
#define Z_OFF      0ull                    // B*S*F      = 8388608
#define QKV_OFF    8388608ull              // B*S*768    = 25165824
#define MEM_OFF    33554432ull             // B*16*F     = 2097152
#define MEMQKV_OFF 35651584ull             // B*16*768   = 6291456
#define PTR_OFF    41943040ull             // B*16       = 8192
#define ZF1_OFF    41951232ull             // B*256      = 131072
#define ZF2_OFF    42082304ull             // B*256      = 131072
#define READ_OFF   42213376ull             // B*256      = 131072
#define PROBS_OFF  42344448ull             // B*128      = 65536
#define QUANT_OFF  42409984ull             // B*256      = 131072
#define HALT_OFF   42541056ull             // B          = 512
#define PVAL_OFF   42541568ull             // B          = 512
#define WACT_OFF   42542080ull             // B          = 512
#define MAGP_OFF   42542592ull             // B*2        = 1024
#define WQKV_OFF   42543616ull             // 196608 floats (WTh+WTl fp16)
#define MQKV_OFF   42740224ull             // 196608 floats (MTh+MTl fp16)
#define CB2_OFF    42936832ull             // 128
// total = 42936960 floats = ~171.7 MB

// ---------------------------------------------------------------------------
__global__ void k_buildwt(const float* __restrict__ wr, const float* __restrict__ wi,
                          half_t* __restrict__ WTh, half_t* __restrict__ WTl) {
    int idx = blockIdx.x * 256 + threadIdx.x;   // 196608 total, grid=768
    if (idx >= 768 * 256) return;
    int col = idx >> 8;     // 0..767
    int e   = idx & 255;
    int h   = col >> 8;
    int c   = col & 255;
    const float* Wr = wr + h * DD * DD;
    const float* Wi = wi + h * DD * DD;
    float v;
    if (c < DD) {
        v = (e < DD) ? Wr[c * DD + e] : -Wi[c * DD + (e - DD)];
    } else {
        int j = c - DD;
        v = (e < DD) ? Wi[j * DD + e] : Wr[j * DD + (e - DD)];
    }
    half_t hh = (half_t)v;
    WTh[idx] = hh;
    WTl[idx] = (half_t)(v - (float)hh);
}

__global__ void k_cb2(const float* __restrict__ cb, float* __restrict__ cb2) {
    int n = threadIdx.x;   // 128 threads
    float s = 0.f;
    for (int c = 0; c < FF; ++c) { float v = cb[n * FF + c]; s += v * v; }
    cb2[n] = s;
}

__global__ __launch_bounds__(256) void k_init(const float* __restrict__ zr_in,
                                              const float* __restrict__ zi_in,
                                              float* __restrict__ z, float* __restrict__ memv,
                                              float* __restrict__ ptrv, float* __restrict__ probs,
                                              float* __restrict__ halt, float* __restrict__ acc) {
    size_t idx = (size_t)blockIdx.x * 256 + threadIdx.x;  // grid 32768 -> 8388608
    int c = (int)(idx & 255);
    size_t bs = idx >> 8;
    z[idx] = (c < DD) ? zr_in[bs * DD + c] : zi_in[bs * DD + (c - DD)];
    acc[idx] = 0.f;
    if (idx < 2097152) memv[idx] = 0.f;
    if (idx < 8192)  ptrv[idx] = ((idx & 15) == 0) ? 1.f : 0.f;
    if (idx < 65536) probs[idx] = 0.f;
    if (idx < 512)   halt[idx] = 0.f;
}

// ---------------------------------------------------------------------------
// Split-fp16 MFMA GEMM: C[M][768] = A[M][256] (fp32) @ W[256][768]
__global__ __launch_bounds__(256) void gemm_split(const float* __restrict__ A,
                                                  const half_t* __restrict__ WTh,
                                                  const half_t* __restrict__ WTl,
                                                  float* __restrict__ C) {
    __shared__ float As[128][36];
    int bm = blockIdx.x / 6;
    int bn = blockIdx.x % 6;
    int tid = threadIdx.x;
    int w = tid >> 6;
    int lane = tid & 63;
    int wr = w >> 1, wc = w & 1;
    int l15 = lane & 15;
    int lq  = lane >> 4;

    f32x4 acc[4][4];
#pragma unroll
    for (int i = 0; i < 4; ++i)
#pragma unroll
        for (int j = 0; j < 4; ++j) acc[i][j] = (f32x4){0.f, 0.f, 0.f, 0.f};

    const float* Ablk = A + (size_t)bm * 128 * 256;
    int colbase = bn * 128 + wc * 64;

    int srow = tid >> 1;
    int sseg = (tid & 1) * 16;

    for (int k0 = 0; k0 < 256; k0 += 32) {
        __syncthreads();
        {
            const float* src = Ablk + (size_t)srow * 256 + k0 + sseg;
            f32x4 v0 = *(const f32x4*)(src);
            f32x4 v1 = *(const f32x4*)(src + 4);
            f32x4 v2 = *(const f32x4*)(src + 8);
            f32x4 v3 = *(const f32x4*)(src + 12);
            *(f32x4*)&As[srow][sseg]      = v0;
            *(f32x4*)&As[srow][sseg + 4]  = v1;
            *(f32x4*)&As[srow][sseg + 8]  = v2;
            *(f32x4*)&As[srow][sseg + 12] = v3;
        }
        __syncthreads();

        half8 bh[4], bl[4];
#pragma unroll
        for (int tj = 0; tj < 4; ++tj) {
            size_t off = (size_t)(colbase + tj * 16 + l15) * 256 + k0 + lq * 8;
            bh[tj] = *(const half8*)(WTh + off);
            bl[tj] = *(const half8*)(WTl + off);
        }

        half8 ah[4], al[4];
#pragma unroll
        for (int ti = 0; ti < 4; ++ti) {
            const float* ap = &As[wr * 64 + ti * 16 + l15][lq * 8];
            f32x4 a0 = *(const f32x4*)(ap);
            f32x4 a1 = *(const f32x4*)(ap + 4);
#pragma unroll
            for (int j = 0; j < 4; ++j) {
                float x = a0[j];
                half_t h = (half_t)x;
                ah[ti][j] = h;
                al[ti][j] = (half_t)(x - (float)h);
            }
#pragma unroll
            for (int j = 0; j < 4; ++j) {
                float x = a1[j];
                half_t h = (half_t)x;
                ah[ti][4 + j] = h;
                al[ti][4 + j] = (half_t)(x - (float)h);
            }
        }

#pragma unroll
        for (int ti = 0; ti < 4; ++ti)
#pragma unroll
            for (int tj = 0; tj < 4; ++tj)
                acc[ti][tj] = __builtin_amdgcn_mfma_f32_16x16x32_f16(ah[ti], bh[tj], acc[ti][tj], 0, 0, 0);
#pragma unroll
        for (int ti = 0; ti < 4; ++ti)
#pragma unroll
            for (int tj = 0; tj < 4; ++tj)
                acc[ti][tj] = __builtin_amdgcn_mfma_f32_16x16x32_f16(ah[ti], bl[tj], acc[ti][tj], 0, 0, 0);
#pragma unroll
        for (int ti = 0; ti < 4; ++ti)
#pragma unroll
            for (int tj = 0; tj < 4; ++tj)
                acc[ti][tj] = __builtin_amdgcn_mfma_f32_16x16x32_f16(al[ti], bh[tj], acc[ti][tj], 0, 0, 0);
    }

    float* Cb = C + (size_t)(bm * 128 + wr * 64) * 768 + bn * 128 + wc * 64;
#pragma unroll
    for (int ti = 0; ti < 4; ++ti)
#pragma unroll
        for (int tj = 0; tj < 4; ++tj) {
            int r0 = ti * 16 + lq * 4;
            int c0 = tj * 16 + l15;
#pragma unroll
            for (int r = 0; r < 4; ++r)
                Cb[(size_t)(r0 + r) * 768 + c0] = acc[ti][tj][r];
        }
}

// ---------------------------------------------------------------------------
// MFMA attention (split fp16, 3-term). One block (4 waves) per batch.
// Swapped QK^T: S^T = K @ Q^T so each lane (l15 = query i) owns a full score
// row across its 4 lq-partners -> softmax = 16 local + shfl_xor(16,32).
// P bounced through per-wave-private LDS (no __syncthreads until zf1 reduce).
__global__ __launch_bounds__(256) void k_attn_mfma(const float* __restrict__ qkv,
                                                   float* __restrict__ z,
                                                   float* __restrict__ zf1) {
    __shared__ half_t PhS[4][16][72];
    __shared__ half_t PlS[4][16][72];
    __shared__ float zfred[4][256];
    int b = blockIdx.x, tid = threadIdx.x;
    int w = tid >> 6, lane = tid & 63;
    int l15 = lane & 15, lq = lane >> 4;
    const float* qkvb = qkv + (size_t)b * SS * 768;

    // ---- QK^T (swapped): sac[jt] = S^T tile, rows j = jt*16+lq*4+r, col i = w*16+l15
    f32x4 sac[4];
#pragma unroll
    for (int jt = 0; jt < 4; ++jt) sac[jt] = (f32x4){0.f, 0.f, 0.f, 0.f};

#pragma unroll
    for (int kt = 0; kt < 8; ++kt) {
        // Q B-fragment (n = i band of this wave)
        const float* qp = qkvb + (size_t)(w * 16 + l15) * 768 + kt * 32 + lq * 8;
        f32x4 q0 = *(const f32x4*)(qp);
        f32x4 q1 = *(const f32x4*)(qp + 4);
        half8 qh, ql;
#pragma unroll
        for (int j = 0; j < 4; ++j) {
            float x = q0[j]; half_t h = (half_t)x;
            qh[j] = h; ql[j] = (half_t)(x - (float)h);
            float y = q1[j]; half_t g = (half_t)y;
            qh[4 + j] = g; ql[4 + j] = (half_t)(y - (float)g);
        }
#pragma unroll
        for (int jt = 0; jt < 4; ++jt) {
            const float* kp = qkvb + (size_t)(jt * 16 + l15) * 768 + 256 + kt * 32 + lq * 8;
            f32x4 k0 = *(const f32x4*)(kp);
            f32x4 k1 = *(const f32x4*)(kp + 4);
            half8 ah, al;
#pragma unroll
            for (int j = 0; j < 4; ++j) {
                float x = k0[j]; half_t h = (half_t)x;
                ah[j] = h; al[j] = (half_t)(x - (float)h);
                float y = k1[j]; half_t g = (half_t)y;
                ah[4 + j] = g; al[4 + j] = (half_t)(y - (float)g);
            }
            sac[jt] = __builtin_amdgcn_mfma_f32_16x16x32_f16(ah, qh, sac[jt], 0, 0, 0);
            sac[jt] = __builtin_amdgcn_mfma_f32_16x16x32_f16(ah, ql, sac[jt], 0, 0, 0);
            sac[jt] = __builtin_amdgcn_mfma_f32_16x16x32_f16(al, qh, sac[jt], 0, 0, 0);
        }
    }

    // ---- softmax over j (rows of S^T) for this lane's query i
    const float scale = 0.08838834764831845f;
    float sv[4][4];
    float mx = -1e30f;
#pragma unroll
    for (int jt = 0; jt < 4; ++jt)
#pragma unroll
        for (int r = 0; r < 4; ++r) {
            float s = sac[jt][r] * scale;
            sv[jt][r] = s;
            mx = fmaxf(mx, s);
        }
    mx = fmaxf(mx, __shfl_xor(mx, 16));
    mx = fmaxf(mx, __shfl_xor(mx, 32));
    float ssum = 0.f;
#pragma unroll
    for (int jt = 0; jt < 4; ++jt)
#pragma unroll
        for (int r = 0; r < 4; ++r) {
            float e = expf(sv[jt][r] - mx);
            sv[jt][r] = e;
            ssum += e;
        }
    ssum += __shfl_xor(ssum, 16);
    ssum += __shfl_xor(ssum, 32);
    float inv = 1.f / ssum;

    // ---- write P (split fp16) to per-wave LDS: Ph[i=l15][j]
#pragma unroll
    for (int jt = 0; jt < 4; ++jt) {
        half4 h4, l4;
#pragma unroll
        for (int r = 0; r < 4; ++r) {
            float pv = sv[jt][r] * inv;
            half_t hh = (half_t)pv;
            h4[r] = hh;
            l4[r] = (half_t)(pv - (float)hh);
        }
        *(half4*)&PhS[w][l15][jt * 16 + lq * 4] = h4;
        *(half4*)&PlS[w][l15][jt * 16 + lq * 4] = l4;
    }

    // ---- PV: O[i][c] = P @ V, V fragments gathered from global (L2)
    f32x4 oac[16];
#pragma unroll
    for (int nt = 0; nt < 16; ++nt) oac[nt] = (f32x4){0.f, 0.f, 0.f, 0.f};

#pragma unroll
    for (int kt2 = 0; kt2 < 2; ++kt2) {
        half8 ph = *(const half8*)&PhS[w][l15][kt2 * 32 + lq * 8];
        half8 pl = *(const half8*)&PlS[w][l15][kt2 * 32 + lq * 8];
        const float* vbase = qkvb + 512 + (size_t)(kt2 * 32 + lq * 8) * 768 + l15;
#pragma unroll
        for (int nt = 0; nt < 16; ++nt) {
            half8 vh, vl;
#pragma unroll
            for (int d = 0; d < 8; ++d) {
                float x = vbase[(size_t)d * 768 + nt * 16];
                half_t h = (half_t)x;
                vh[d] = h;
                vl[d] = (half_t)(x - (float)h);
            }
            oac[nt] = __builtin_amdgcn_mfma_f32_16x16x32_f16(ph, vh, oac[nt], 0, 0, 0);
            oac[nt] = __builtin_amdgcn_mfma_f32_16x16x32_f16(ph, vl, oac[nt], 0, 0, 0);
            oac[nt] = __builtin_amdgcn_mfma_f32_16x16x32_f16(pl, vh, oac[nt], 0, 0, 0);
        }
    }

    // ---- residual z update + zf1 partials
    float* zb = z + (size_t)b * (SS * FF);
    float zfl[16];
#pragma unroll
    for (int nt = 0; nt < 16; ++nt) {
        float s = 0.f;
#pragma unroll
        for (int r = 0; r < 4; ++r) {
            int i = w * 16 + lq * 4 + r;
            int c = nt * 16 + l15;
            float zo = zb[(size_t)i * 256 + c];
            float zn = oac[nt][r] + 0.1f * zo;
            zb[(size_t)i * 256 + c] = zn;
            s += zn;
        }
        s += __shfl_xor(s, 16);
        s += __shfl_xor(s, 32);
        zfl[nt] = s;
    }
    if (lq == 0) {
#pragma unroll
        for (int nt = 0; nt < 16; ++nt) zfred[w][nt * 16 + l15] = zfl[nt];
    }
    __syncthreads();
    zf1[b * FF + tid] = (zfred[0][tid] + zfred[1][tid] + zfred[2][tid] + zfred[3][tid]) * (1.f / 64.f);
}

// ---------------------------------------------------------------------------
// Gate + pointer + memory update.  1 block/batch, 256 threads.
__global__ __launch_bounds__(256) void k_gate(const float* __restrict__ zf1,
                                              const float* __restrict__ ctrl_w,
                                              const float* __restrict__ ctrl_b,
                                              float* __restrict__ ptrv,
                                              float* __restrict__ memv) {
    __shared__ float zf[256];
    __shared__ float g[3];
    __shared__ float oldp[16];
    int b = blockIdx.x, tid = threadIdx.x;
    zf[tid] = zf1[b * FF + tid];
    if (tid < 16) oldp[tid] = ptrv[b * STK + tid];
    __syncthreads();
    int w = tid >> 6, lane = tid & 63;
    if (w < 3) {
        float s = 0.f;
#pragma unroll
        for (int q = 0; q < 4; ++q) {
            int c = lane + 64 * q;
            s += zf[c] * ctrl_w[c * 3 + w];
        }
#pragma unroll
        for (int off = 1; off < 64; off <<= 1) s += __shfl_xor(s, off);
        if (lane == 0) g[w] = 1.f / (1.f + expf(-(s + ctrl_b[w])));
    }
    __syncthreads();
    float tot = g[0] + g[1] + g[2] + 1e-6f;
    float push = g[0] / tot, pop = g[1] / tot, stay = g[2] / tot;
    if (tid < 16) {
        int s = tid;
        float np = push * oldp[(s + 15) & 15] + pop * oldp[(s + 1) & 15] + stay * oldp[s];
        ptrv[b * STK + s] = np;
    }
    for (int idx = tid; idx < STK * FF; idx += 256) {
        int c = idx & 255;
        size_t gi = (size_t)b * (STK * FF) + idx;
        float m = memv[gi];
        memv[gi] = m * (1.f - push) + push * zf[c];
    }
}

// ---------------------------------------------------------------------------
// Memory attention + pointer-weighted read.  1 block/batch, 256 threads.
__global__ __launch_bounds__(256) void k_memattn(const float* __restrict__ memqkv,
                                                 const float* __restrict__ ptrv,
                                                 float* __restrict__ readv) {
    __shared__ float mq[16][257];
    __shared__ float mk[16][257];
    __shared__ float mv[16][257];
    __shared__ float sm[16][17];
    __shared__ float rowmax[16], rowsum[16], pw[16];
    int b = blockIdx.x, tid = threadIdx.x;
    const float* mb = memqkv + (size_t)b * STK * 768;
    for (int idx = tid; idx < STK * FF; idx += 256) {
        int t = idx >> 8, c = idx & 255;
        mq[t][c] = mb[t * 768 + c];
        mk[t][c] = mb[t * 768 + 256 + c];
        mv[t][c] = mb[t * 768 + 512 + c];
    }
    __syncthreads();
    int i = tid >> 4, j = tid & 15;
    float s = 0.f;
#pragma unroll 8
    for (int c = 0; c < 256; ++c) s += mq[i][c] * mk[j][c];
    s *= 0.08838834764831845f;
    sm[i][j] = s;
    __syncthreads();
    if (tid < 16) {
        float m = -1e30f;
        for (int jj = 0; jj < 16; ++jj) m = fmaxf(m, sm[tid][jj]);
        float su = 0.f;
        for (int jj = 0; jj < 16; ++jj) su += expf(sm[tid][jj] - m);
        rowmax[tid] = m; rowsum[tid] = su;
    }
    __syncthreads();
    float p = expf(s - rowmax[i]) / rowsum[i];
    sm[i][j] = p;
    __syncthreads();
    if (tid < 16) {
        float a = 0.f;
        for (int ss2 = 0; ss2 < 16; ++ss2) a += ptrv[b * STK + ss2] * sm[ss2][tid];
        pw[tid] = a;
    }
    __syncthreads();
    {
        int c = tid;
        float a = 0.f;
#pragma unroll
        for (int jj = 0; jj < 16; ++jj) a += pw[jj] * mv[jj][c];
        readv[b * FF + c] = a;
    }
}

// ---------------------------------------------------------------------------
__device__ __forceinline__ float bredsum(float v, float* red, int n) {
    red[n] = v; __syncthreads();
    for (int off = 64; off > 0; off >>= 1) {
        if (n < off) red[n] += red[n + off];
        __syncthreads();
    }
    float r = red[0];
    __syncthreads();
    return r;
}
__device__ __forceinline__ float bredmax(float v, float* red, int n) {
    red[n] = v; __syncthreads();
    for (int off = 64; off > 0; off >>= 1) {
        if (n < off) red[n] = fmaxf(red[n], red[n + off]);
        __syncthreads();
    }
    float r = red[0];
    __syncthreads();
    return r;
}

// z += 0.1*read; zf2 = mean; mag partial sums; halting logit. 1 blk/batch, 128 thr.
__global__ __launch_bounds__(128) void k_zup2(float* __restrict__ z,
                                              const float* __restrict__ readv,
                                              float* __restrict__ zf2,
                                              const float* __restrict__ halt_w,
                                              const float* __restrict__ halt_b,
                                              float* __restrict__ pval,
                                              float* __restrict__ magpart) {
    __shared__ float red[128];
    int b = blockIdx.x, d = threadIdx.x;
    float rr = 0.1f * readv[b * FF + d];
    float ri = 0.1f * readv[b * FF + DD + d];
    float sr = 0.f, si = 0.f, ms = 0.f, msq = 0.f;
    float* zb = z + (size_t)b * (SS * FF);
    for (int s = 0; s < SS; ++s) {
        float zr = zb[s * FF + d] + rr;
        float zi = zb[s * FF + DD + d] + ri;
        zb[s * FF + d] = zr;
        zb[s * FF + DD + d] = zi;
        sr += zr; si += zi;
        float m2 = zr * zr + zi * zi;
        ms += sqrtf(m2); msq += m2;
    }
    float zfr = sr * (1.f / 64.f), zfi = si * (1.f / 64.f);
    zf2[b * FF + d] = zfr;
    zf2[b * FF + DD + d] = zfi;
    float tms = bredsum(ms, red, d);
    float tmsq = bredsum(msq, red, d);
    if (d == 0) { magpart[2 * b] = tms; magpart[2 * b + 1] = tmsq; }
    float hp = zfr * halt_w[d] + zfi * halt_w[DD + d];
    float thp = bredsum(hp, red, d);
    if (d == 0) pval[b] = 1.f / (1.f + expf(-(thp + halt_b[0])));
}

// VQ + ACT bookkeeping. 1 block/batch, 128 threads (one per symbol).
__global__ __launch_bounds__(128) void k_vq(const float* __restrict__ zf2,
                                            const float* __restrict__ cb,
                                            const float* __restrict__ cb2,
                                            const float* __restrict__ adj,
                                            float* __restrict__ probs,
                                            float* __restrict__ quant,
                                            float* __restrict__ halt,
                                            const float* __restrict__ pval,
                                            float* __restrict__ wact,
                                            const float* __restrict__ magpart, int t) {
    __shared__ float red[128];
    __shared__ float zf[256];
    __shared__ float pr[128];
    int b = blockIdx.x, n = threadIdx.x;
    zf[n] = zf2[b * FF + n];
    zf[DD + n] = zf2[b * FF + DD + n];
    float up = 0.f;
    if (t > 0) {
        float pa = 0.f, pb = 0.f;
        for (int k = n; k < BB; k += 128) { pa += magpart[2 * k]; pb += magpart[2 * k + 1]; }
        float tms = bredsum(pa, red, n);
        float tmsq = bredsum(pb, red, n);
        const float N = 4194304.f;   // B*S*D
        float mean = tms / N;
        float var = tmsq / N - mean * mean;
        float x = var / (1.f + 1e-6f);
        up = (x > 20.f) ? x : log1pf(expf(x));
    }
    __syncthreads();
    float part = zf[n] * zf[n] + zf[DD + n] * zf[DD + n];
    float zz = bredsum(part, red, n);
    float dot = 0.f;
    const float* cbn = cb + n * FF;
#pragma unroll 8
    for (int c = 0; c < FF; ++c) dot += zf[c] * cbn[c];
    float dist = (zz + cb2[n] - 2.f * dot) * (1.f / 256.f);
    float dtot = dist;
    if (t > 0) {
        float gb = 0.f;
        const float* pp = probs + b * NSYM;
        for (int k = 0; k < NSYM; ++k) gb += pp[k] * adj[k * NSYM + n];
        dtot = dist - 0.01f * up * (1.f / (1.f + expf(-gb)));
    }
    float v = -dtot;   // TEMP = 1
    float mx = bredmax(v, red, n);
    float e = expf(v - mx);
    float se = bredsum(e, red, n);
    float psm = e / se;
    pr[n] = psm;
    __syncthreads();
    probs[b * NSYM + n] = psm;
    float q0 = 0.f, q1 = 0.f;
    for (int k = 0; k < NSYM; ++k) {
        float pk = pr[k];
        q0 += pk * cb[k * FF + n];
        q1 += pk * cb[k * FF + DD + n];
    }
    quant[b * FF + n] = q0;
    quant[b * FF + DD + n] = q1;
    if (n == 0) {
        float h = halt[b], p = pval[b];
        float running = (h < 0.99f) ? 1.f : 0.f;
        float w = (((h + p * running) >= 0.99f) ? (1.f - h) : p) * running;
        halt[b] = h + w;
        wact[b] = w;
    }
}

// z += 0.1*quant (broadcast over S); acc += w*z
__global__ __launch_bounds__(256) void k_final(float* __restrict__ z,
                                               const float* __restrict__ quant,
                                               const float* __restrict__ wact,
                                               float* __restrict__ acc) {
    int idx = blockIdx.x * 256 + threadIdx.x;   // grid 32768 -> 8388608
    int b = idx >> 14;     // /(S*F)
    int c = idx & 255;
    float zv = z[idx] + 0.1f * quant[b * FF + c];
    z[idx] = zv;
    acc[idx] += wact[b] * zv;
}

// ---------------------------------------------------------------------------
extern "C" void kernel_launch(void* const* d_in, const int* in_sizes, int n_in,
                              void* d_out, int out_size, void* d_ws, size_t ws_size,
                              hipStream_t stream) {
    const float* z_real  = (const float*)d_in[0];
    const float* z_imag  = (const float*)d_in[1];
    const float* attn_wr = (const float*)d_in[2];
    const float* attn_wi = (const float*)d_in[3];
    const float* mem_wr  = (const float*)d_in[4];
    const float* mem_wi  = (const float*)d_in[5];
    const float* ctrl_w  = (const float*)d_in[6];
    const float* ctrl_b  = (const float*)d_in[7];
    const float* halt_w  = (const float*)d_in[8];
    const float* halt_b  = (const float*)d_in[9];
    const float* codebook  = (const float*)d_in[10];
    const float* adjacency = (const float*)d_in[11];

    float* ws = (float*)d_ws;
    float* z      = ws + Z_OFF;
    float* qkv    = ws + QKV_OFF;
    float* memv   = ws + MEM_OFF;
    float* memqkv = ws + MEMQKV_OFF;
    float* ptrv   = ws + PTR_OFF;
    float* zf1    = ws + ZF1_OFF;
    float* zf2    = ws + ZF2_OFF;
    float* readv  = ws + READ_OFF;
    float* probs  = ws + PROBS_OFF;
    float* quant  = ws + QUANT_OFF;
    float* halt   = ws + HALT_OFF;
    float* pval   = ws + PVAL_OFF;
    float* wact   = ws + WACT_OFF;
    float* magp   = ws + MAGP_OFF;
    half_t* WTh_a = (half_t*)(ws + WQKV_OFF);
    half_t* WTl_a = (half_t*)(ws + WQKV_OFF) + 196608;
    half_t* WTh_m = (half_t*)(ws + MQKV_OFF);
    half_t* WTl_m = (half_t*)(ws + MQKV_OFF) + 196608;
    float* cb2    = ws + CB2_OFF;
    float* acc    = (float*)d_out;

    k_buildwt<<<768, 256, 0, stream>>>(attn_wr, attn_wi, WTh_a, WTl_a);
    k_buildwt<<<768, 256, 0, stream>>>(mem_wr, mem_wi, WTh_m, WTl_m);
    k_cb2<<<1, 128, 0, stream>>>(codebook, cb2);
    k_init<<<32768, 256, 0, stream>>>(z_real, z_imag, z, memv, ptrv, probs, halt, acc);

    for (int t = 0; t < NDEPTH; ++t) {
        gemm_split<<<(BB * SS / 128) * 6, 256, 0, stream>>>(z, WTh_a, WTl_a, qkv);        // 1536 blocks
        k_attn_mfma<<<BB, 256, 0, stream>>>(qkv, z, zf1);
        k_gate<<<BB, 256, 0, stream>>>(zf1, ctrl_w, ctrl_b, ptrv, memv);
        gemm_split<<<(BB * STK / 128) * 6, 256, 0, stream>>>(memv, WTh_m, WTl_m, memqkv); // 384 blocks
        k_memattn<<<BB, 256, 0, stream>>>(memqkv, ptrv, readv);
        k_zup2<<<BB, 128, 0, stream>>>(z, readv, zf2, halt_w, halt_b, pval, magp);
        k_vq<<<BB, 128, 0, stream>>>(zf2, codebook, cb2, adjacency, probs, quant,
                                     halt, pval, wact, magp, t);
        k_final<<<32768, 256, 0, stream>>>(z, quant, wact, acc);
    }
}

// Round 4
// 1159.281 us; speedup vs baseline: 3.3897x; 1.4640x over previous
//
#include <hip/hip_runtime.h>
#include <math.h>

// Problem constants
#define BB 512
#define SS 64
#define DD 128
#define FF 256   // 2D
#define NSYM 128
#define STK 16
#define NDEPTH 8

typedef _Float16 half_t;
typedef __attribute__((ext_vector_type(4))) _Float16 half4;
typedef __attribute__((ext_vector_type(8))) _Float16 half8;
typedef __attribute__((ext_vector_type(4))) float f32x4;

// Workspace offsets (in floats)
#define Z_OFF      0ull                    // B*S*F      = 8388608
#define QKV_OFF    8388608ull              // reused: WT32 + GT/WvT split planes
#define MEM_OFF    33554432ull             // B*16*F     = 2097152
#define MEMQKV_OFF 35651584ull             // B*16*768   = 6291456
#define PTR_OFF    41943040ull             // B*16       = 8192
#define ZF1_OFF    41951232ull             // B*256      = 131072
#define ZF2_OFF    42082304ull             // B*256      = 131072
#define READ_OFF   42213376ull             // B*256      = 131072
#define PROBS_OFF  42344448ull             // B*128      = 65536
#define QUANT_OFF  42409984ull             // B*256      = 131072
#define HALT_OFF   42541056ull             // B          = 512
#define PVAL_OFF   42541568ull             // B          = 512
#define WACT_OFF   42542080ull             // B          = 512
#define MAGP_OFF   42542592ull             // B*2        = 1024
#define WQKV_OFF   42543616ull             // (unused for attn now)
#define MQKV_OFF   42740224ull             // 196608 floats (MTh+MTl fp16)
#define CB2_OFF    42936832ull             // 128

// ---------------------------------------------------------------------------
// Combined transposed weight, fp32: WT32[h][c][e] = W_h[e][c], h in {q,k,v}
__global__ void k_buildwt32(const float* __restrict__ wr, const float* __restrict__ wi,
                            float* __restrict__ WT32) {
    int idx = blockIdx.x * 256 + threadIdx.x;   // 196608 total, grid=768
    if (idx >= 768 * 256) return;
    int col = idx >> 8;     // 0..767 = h*256 + c
    int e   = idx & 255;
    int h   = col >> 8;
    int c   = col & 255;
    const float* Wr = wr + h * DD * DD;
    const float* Wi = wi + h * DD * DD;
    float v;
    if (c < DD) {
        v = (e < DD) ? Wr[c * DD + e] : -Wi[c * DD + (e - DD)];
    } else {
        int j = c - DD;
        v = (e < DD) ? Wi[j * DD + e] : Wr[j * DD + (e - DD)];
    }
    WT32[idx] = v;
}

// GT[n][e] = G[e][n] = sum_c Wq[e][c]*Wk[n][c], split to fp16 h/l.
__global__ __launch_bounds__(256) void k_buildG(const float* __restrict__ WT32,
                                                half_t* __restrict__ GTh,
                                                half_t* __restrict__ GTl) {
    __shared__ float kcol[256];
    int n = blockIdx.x;       // 0..255
    int e = threadIdx.x;      // 0..255
    kcol[e] = WT32[65536 + e * 256 + n];   // Wk[n][c=e]
    __syncthreads();
    float s = 0.f;
    for (int c = 0; c < 256; ++c) s += kcol[c] * WT32[c * 256 + e];  // Wq[e][c]
    half_t h = (half_t)s;
    GTh[n * 256 + e] = h;
    GTl[n * 256 + e] = (half_t)(s - (float)h);
}

__global__ void k_splitWv(const float* __restrict__ WT32,
                          half_t* __restrict__ WvTh, half_t* __restrict__ WvTl) {
    int idx = blockIdx.x * 256 + threadIdx.x;   // 65536, grid 256
    float v = WT32[131072 + idx];   // WvT[n][e] = Wv[e][n]
    half_t h = (half_t)v;
    WvTh[idx] = h;
    WvTl[idx] = (half_t)(v - (float)h);
}

// Memory-path combined transposed split weights (as R2/R3).
__global__ void k_buildwt(const float* __restrict__ wr, const float* __restrict__ wi,
                          half_t* __restrict__ WTh, half_t* __restrict__ WTl) {
    int idx = blockIdx.x * 256 + threadIdx.x;   // 196608 total, grid=768
    if (idx >= 768 * 256) return;
    int col = idx >> 8;
    int e   = idx & 255;
    int h   = col >> 8;
    int c   = col & 255;
    const float* Wr = wr + h * DD * DD;
    const float* Wi = wi + h * DD * DD;
    float v;
    if (c < DD) {
        v = (e < DD) ? Wr[c * DD + e] : -Wi[c * DD + (e - DD)];
    } else {
        int j = c - DD;
        v = (e < DD) ? Wi[j * DD + e] : Wr[j * DD + (e - DD)];
    }
    half_t hh = (half_t)v;
    WTh[idx] = hh;
    WTl[idx] = (half_t)(v - (float)hh);
}

__global__ void k_cb2(const float* __restrict__ cb, float* __restrict__ cb2) {
    int n = threadIdx.x;   // 128 threads
    float s = 0.f;
    for (int c = 0; c < FF; ++c) { float v = cb[n * FF + c]; s += v * v; }
    cb2[n] = s;
}

__global__ __launch_bounds__(256) void k_init(const float* __restrict__ zr_in,
                                              const float* __restrict__ zi_in,
                                              float* __restrict__ z, float* __restrict__ memv,
                                              float* __restrict__ ptrv, float* __restrict__ probs,
                                              float* __restrict__ halt, float* __restrict__ acc,
                                              float* __restrict__ quant, float* __restrict__ wact) {
    size_t idx = (size_t)blockIdx.x * 256 + threadIdx.x;  // grid 32768 -> 8388608
    int c = (int)(idx & 255);
    size_t bs = idx >> 8;
    z[idx] = (c < DD) ? zr_in[bs * DD + c] : zi_in[bs * DD + (c - DD)];
    acc[idx] = 0.f;
    if (idx < 2097152) memv[idx] = 0.f;
    if (idx < 131072) quant[idx] = 0.f;
    if (idx < 8192)  ptrv[idx] = ((idx & 15) == 0) ? 1.f : 0.f;
    if (idx < 65536) probs[idx] = 0.f;
    if (idx < 512)   { halt[idx] = 0.f; wact[idx] = 0.f; }
}

// ---------------------------------------------------------------------------
// Fused per-batch attention step:
//   x0 = z + 0.1*quant_prev (bcast);  acc += wact_prev*x0 (skipped if w==0)
//   T = x0@G (scaled);  S^T = x0@T^T; softmax -> P;  V = x0@Wv (stored V^T);
//   O = P@V^T;  z_out = O + 0.1*x0;  zf1 = mean_s(z_out)
// All GEMMs are 3-term split-fp16 MFMA. One block (4 waves) per batch.
__global__ __launch_bounds__(256, 1) void k_attn_fused(
        float* __restrict__ z,
        const half_t* __restrict__ GTh, const half_t* __restrict__ GTl,
        const half_t* __restrict__ WvTh, const half_t* __restrict__ WvTl,
        const float* __restrict__ quant, const float* __restrict__ wact,
        float* __restrict__ acc, float* __restrict__ zf1) {
    __shared__ half_t Zh[64 * 264], Zl[64 * 264];     // x0 split, row stride 264
    __shared__ half_t Ubuf[2][18432];                 // union: T[64][264] / VT[256][72]
    __shared__ half_t Pbuf[2][4][1152];               // P split per wave [16 i][72 j]
    int b = blockIdx.x, tid = threadIdx.x;
    int w = tid >> 6, lane = tid & 63;
    int l15 = lane & 15, lq = lane >> 4;
    float* zb = z + (size_t)b * (SS * FF);
    float* accb = acc + (size_t)b * (SS * FF);

    // ---- phase 0: load z, apply deferred quant/acc, split to LDS
    float wa = wact[b];
    f32x4 qv = *(const f32x4*)(quant + b * FF + lane * 4);
    bool doacc = (wa != 0.0f);
#pragma unroll
    for (int it = 0; it < 16; ++it) {
        int i = w + it * 4;
        f32x4 zv = *(const f32x4*)(zb + (size_t)i * FF + lane * 4);
        f32x4 x0;
#pragma unroll
        for (int jj = 0; jj < 4; ++jj) x0[jj] = zv[jj] + 0.1f * qv[jj];
        if (doacc) {
            f32x4 av = *(const f32x4*)(accb + (size_t)i * FF + lane * 4);
#pragma unroll
            for (int jj = 0; jj < 4; ++jj) av[jj] += wa * x0[jj];
            *(f32x4*)(accb + (size_t)i * FF + lane * 4) = av;
        }
        half4 h4, l4;
#pragma unroll
        for (int jj = 0; jj < 4; ++jj) {
            half_t h = (half_t)x0[jj];
            h4[jj] = h; l4[jj] = (half_t)(x0[jj] - (float)h);
        }
        *(half4*)&Zh[i * 264 + lane * 4] = h4;
        *(half4*)&Zl[i * 264 + lane * 4] = l4;
    }
    __syncthreads();

    // ---- phase T: T = x0 @ G. Wave w computes cols [w*64, w*64+64), all rows.
    {
        f32x4 tac[4][4];
#pragma unroll
        for (int mt = 0; mt < 4; ++mt)
#pragma unroll
            for (int nt = 0; nt < 4; ++nt) tac[mt][nt] = (f32x4){0.f, 0.f, 0.f, 0.f};
        for (int kt = 0; kt < 8; ++kt) {
            int k0 = kt * 32;
            half8 zah[4], zal[4], gh[4], gl[4];
#pragma unroll
            for (int mt = 0; mt < 4; ++mt) {
                int ro = (mt * 16 + l15) * 264 + k0 + lq * 8;
                zah[mt] = *(const half8*)&Zh[ro];
                zal[mt] = *(const half8*)&Zl[ro];
            }
#pragma unroll
            for (int nt = 0; nt < 4; ++nt) {
                size_t off = (size_t)(w * 64 + nt * 16 + l15) * 256 + k0 + lq * 8;
                gh[nt] = *(const half8*)(GTh + off);
                gl[nt] = *(const half8*)(GTl + off);
            }
#pragma unroll
            for (int mt = 0; mt < 4; ++mt)
#pragma unroll
                for (int nt = 0; nt < 4; ++nt)
                    tac[mt][nt] = __builtin_amdgcn_mfma_f32_16x16x32_f16(zah[mt], gh[nt], tac[mt][nt], 0, 0, 0);
#pragma unroll
            for (int mt = 0; mt < 4; ++mt)
#pragma unroll
                for (int nt = 0; nt < 4; ++nt)
                    tac[mt][nt] = __builtin_amdgcn_mfma_f32_16x16x32_f16(zah[mt], gl[nt], tac[mt][nt], 0, 0, 0);
#pragma unroll
            for (int mt = 0; mt < 4; ++mt)
#pragma unroll
                for (int nt = 0; nt < 4; ++nt)
                    tac[mt][nt] = __builtin_amdgcn_mfma_f32_16x16x32_f16(zal[mt], gh[nt], tac[mt][nt], 0, 0, 0);
        }
        const float scale = 0.08838834764831845f;   // 128^-0.5, folded into T
#pragma unroll
        for (int mt = 0; mt < 4; ++mt)
#pragma unroll
            for (int nt = 0; nt < 4; ++nt)
#pragma unroll
                for (int r = 0; r < 4; ++r) {
                    int m = mt * 16 + lq * 4 + r;
                    int n = w * 64 + nt * 16 + l15;
                    float v = tac[mt][nt][r] * scale;
                    half_t h = (half_t)v;
                    Ubuf[0][m * 264 + n] = h;
                    Ubuf[1][m * 264 + n] = (half_t)(v - (float)h);
                }
    }
    __syncthreads();

    // ---- phase S: S^T = x0 @ T^T (cols i = this wave's 16 queries); softmax; P
    {
        f32x4 sac[4];
#pragma unroll
        for (int jt = 0; jt < 4; ++jt) sac[jt] = (f32x4){0.f, 0.f, 0.f, 0.f};
        for (int kt = 0; kt < 8; ++kt) {
            int k0 = kt * 32;
            int to = (w * 16 + l15) * 264 + k0 + lq * 8;
            half8 bh = *(const half8*)&Ubuf[0][to];
            half8 bl = *(const half8*)&Ubuf[1][to];
            half8 ah[4], al[4];
#pragma unroll
            for (int jt = 0; jt < 4; ++jt) {
                int ro = (jt * 16 + l15) * 264 + k0 + lq * 8;
                ah[jt] = *(const half8*)&Zh[ro];
                al[jt] = *(const half8*)&Zl[ro];
            }
#pragma unroll
            for (int jt = 0; jt < 4; ++jt)
                sac[jt] = __builtin_amdgcn_mfma_f32_16x16x32_f16(ah[jt], bh, sac[jt], 0, 0, 0);
#pragma unroll
            for (int jt = 0; jt < 4; ++jt)
                sac[jt] = __builtin_amdgcn_mfma_f32_16x16x32_f16(ah[jt], bl, sac[jt], 0, 0, 0);
#pragma unroll
            for (int jt = 0; jt < 4; ++jt)
                sac[jt] = __builtin_amdgcn_mfma_f32_16x16x32_f16(al[jt], bh, sac[jt], 0, 0, 0);
        }
        float sv[4][4];
        float mx = -1e30f;
#pragma unroll
        for (int jt = 0; jt < 4; ++jt)
#pragma unroll
            for (int r = 0; r < 4; ++r) {
                float s = sac[jt][r];
                sv[jt][r] = s;
                mx = fmaxf(mx, s);
            }
        mx = fmaxf(mx, __shfl_xor(mx, 16));
        mx = fmaxf(mx, __shfl_xor(mx, 32));
        float ssum = 0.f;
#pragma unroll
        for (int jt = 0; jt < 4; ++jt)
#pragma unroll
            for (int r = 0; r < 4; ++r) {
                float e = expf(sv[jt][r] - mx);
                sv[jt][r] = e;
                ssum += e;
            }
        ssum += __shfl_xor(ssum, 16);
        ssum += __shfl_xor(ssum, 32);
        float inv = 1.f / ssum;
#pragma unroll
        for (int jt = 0; jt < 4; ++jt) {
            half4 h4, l4;
#pragma unroll
            for (int r = 0; r < 4; ++r) {
                float pv = sv[jt][r] * inv;
                half_t hh = (half_t)pv;
                h4[r] = hh;
                l4[r] = (half_t)(pv - (float)hh);
            }
            *(half4*)&Pbuf[0][w][l15 * 72 + jt * 16 + lq * 4] = h4;
            *(half4*)&Pbuf[1][w][l15 * 72 + jt * 16 + lq * 4] = l4;
        }
    }
    __syncthreads();   // all T reads done before VT overwrites Ubuf

    // ---- phase V: V = x0 @ Wv, written transposed VT[n][m] into Ubuf
    {
        f32x4 vac[4][4];
#pragma unroll
        for (int mt = 0; mt < 4; ++mt)
#pragma unroll
            for (int nt = 0; nt < 4; ++nt) vac[mt][nt] = (f32x4){0.f, 0.f, 0.f, 0.f};
        for (int kt = 0; kt < 8; ++kt) {
            int k0 = kt * 32;
            half8 zah[4], zal[4], gh[4], gl[4];
#pragma unroll
            for (int mt = 0; mt < 4; ++mt) {
                int ro = (mt * 16 + l15) * 264 + k0 + lq * 8;
                zah[mt] = *(const half8*)&Zh[ro];
                zal[mt] = *(const half8*)&Zl[ro];
            }
#pragma unroll
            for (int nt = 0; nt < 4; ++nt) {
                size_t off = (size_t)(w * 64 + nt * 16 + l15) * 256 + k0 + lq * 8;
                gh[nt] = *(const half8*)(WvTh + off);
                gl[nt] = *(const half8*)(WvTl + off);
            }
#pragma unroll
            for (int mt = 0; mt < 4; ++mt)
#pragma unroll
                for (int nt = 0; nt < 4; ++nt)
                    vac[mt][nt] = __builtin_amdgcn_mfma_f32_16x16x32_f16(zah[mt], gh[nt], vac[mt][nt], 0, 0, 0);
#pragma unroll
            for (int mt = 0; mt < 4; ++mt)
#pragma unroll
                for (int nt = 0; nt < 4; ++nt)
                    vac[mt][nt] = __builtin_amdgcn_mfma_f32_16x16x32_f16(zah[mt], gl[nt], vac[mt][nt], 0, 0, 0);
#pragma unroll
            for (int mt = 0; mt < 4; ++mt)
#pragma unroll
                for (int nt = 0; nt < 4; ++nt)
                    vac[mt][nt] = __builtin_amdgcn_mfma_f32_16x16x32_f16(zal[mt], gh[nt], vac[mt][nt], 0, 0, 0);
        }
#pragma unroll
        for (int mt = 0; mt < 4; ++mt)
#pragma unroll
            for (int nt = 0; nt < 4; ++nt) {
                int n = w * 64 + nt * 16 + l15;
                int m0 = mt * 16 + lq * 4;
                half4 h4, l4;
#pragma unroll
                for (int r = 0; r < 4; ++r) {
                    float v = vac[mt][nt][r];
                    half_t h = (half_t)v;
                    h4[r] = h; l4[r] = (half_t)(v - (float)h);
                }
                *(half4*)&Ubuf[0][n * 72 + m0] = h4;
                *(half4*)&Ubuf[1][n * 72 + m0] = l4;
            }
    }
    __syncthreads();

    // ---- phase O: O = P @ V^T; residual; zf1 partials
    float zfl[16];
    {
        f32x4 oac[16];
#pragma unroll
        for (int nt = 0; nt < 16; ++nt) oac[nt] = (f32x4){0.f, 0.f, 0.f, 0.f};
        for (int kt = 0; kt < 2; ++kt) {
            int k0 = kt * 32;
            half8 ph = *(const half8*)&Pbuf[0][w][l15 * 72 + k0 + lq * 8];
            half8 pl = *(const half8*)&Pbuf[1][w][l15 * 72 + k0 + lq * 8];
#pragma unroll
            for (int nc = 0; nc < 4; ++nc) {
                half8 vh[4], vl[4];
#pragma unroll
                for (int q = 0; q < 4; ++q) {
                    int n = (nc * 4 + q) * 16 + l15;
                    vh[q] = *(const half8*)&Ubuf[0][n * 72 + k0 + lq * 8];
                    vl[q] = *(const half8*)&Ubuf[1][n * 72 + k0 + lq * 8];
                }
#pragma unroll
                for (int q = 0; q < 4; ++q)
                    oac[nc * 4 + q] = __builtin_amdgcn_mfma_f32_16x16x32_f16(ph, vh[q], oac[nc * 4 + q], 0, 0, 0);
#pragma unroll
                for (int q = 0; q < 4; ++q)
                    oac[nc * 4 + q] = __builtin_amdgcn_mfma_f32_16x16x32_f16(ph, vl[q], oac[nc * 4 + q], 0, 0, 0);
#pragma unroll
                for (int q = 0; q < 4; ++q)
                    oac[nc * 4 + q] = __builtin_amdgcn_mfma_f32_16x16x32_f16(pl, vh[q], oac[nc * 4 + q], 0, 0, 0);
            }
        }
        // residual + z write + zf partials
#pragma unroll
        for (int nt = 0; nt < 16; ++nt) {
            float s = 0.f;
#pragma unroll
            for (int r = 0; r < 4; ++r) {
                int i = w * 16 + lq * 4 + r;
                int c = nt * 16 + l15;
                float x0 = (float)Zh[i * 264 + c] + (float)Zl[i * 264 + c];
                float x1 = oac[nt][r] + 0.1f * x0;
                zb[(size_t)i * FF + c] = x1;
                s += x1;
            }
            s += __shfl_xor(s, 16);
            s += __shfl_xor(s, 32);
            zfl[nt] = s;
        }
    }
    __syncthreads();
    float* zfred = (float*)&Pbuf[0][0][0];
    if (lq == 0) {
#pragma unroll
        for (int nt = 0; nt < 16; ++nt) zfred[w * 256 + nt * 16 + l15] = zfl[nt];
    }
    __syncthreads();
    zf1[b * FF + tid] = (zfred[tid] + zfred[256 + tid] + zfred[512 + tid] + zfred[768 + tid]) * (1.f / 64.f);
}

// ---------------------------------------------------------------------------
// Split-fp16 MFMA GEMM (memory path): C[M][768] = A[M][256] @ W[256][768]
__global__ __launch_bounds__(256) void gemm_split(const float* __restrict__ A,
                                                  const half_t* __restrict__ WTh,
                                                  const half_t* __restrict__ WTl,
                                                  float* __restrict__ C) {
    __shared__ float As[128][36];
    int bm = blockIdx.x / 6;
    int bn = blockIdx.x % 6;
    int tid = threadIdx.x;
    int w = tid >> 6;
    int lane = tid & 63;
    int wr = w >> 1, wc = w & 1;
    int l15 = lane & 15;
    int lq  = lane >> 4;

    f32x4 acc[4][4];
#pragma unroll
    for (int i = 0; i < 4; ++i)
#pragma unroll
        for (int j = 0; j < 4; ++j) acc[i][j] = (f32x4){0.f, 0.f, 0.f, 0.f};

    const float* Ablk = A + (size_t)bm * 128 * 256;
    int colbase = bn * 128 + wc * 64;

    int srow = tid >> 1;
    int sseg = (tid & 1) * 16;

    for (int k0 = 0; k0 < 256; k0 += 32) {
        __syncthreads();
        {
            const float* src = Ablk + (size_t)srow * 256 + k0 + sseg;
            f32x4 v0 = *(const f32x4*)(src);
            f32x4 v1 = *(const f32x4*)(src + 4);
            f32x4 v2 = *(const f32x4*)(src + 8);
            f32x4 v3 = *(const f32x4*)(src + 12);
            *(f32x4*)&As[srow][sseg]      = v0;
            *(f32x4*)&As[srow][sseg + 4]  = v1;
            *(f32x4*)&As[srow][sseg + 8]  = v2;
            *(f32x4*)&As[srow][sseg + 12] = v3;
        }
        __syncthreads();

        half8 bh[4], bl[4];
#pragma unroll
        for (int tj = 0; tj < 4; ++tj) {
            size_t off = (size_t)(colbase + tj * 16 + l15) * 256 + k0 + lq * 8;
            bh[tj] = *(const half8*)(WTh + off);
            bl[tj] = *(const half8*)(WTl + off);
        }

        half8 ah[4], al[4];
#pragma unroll
        for (int ti = 0; ti < 4; ++ti) {
            const float* ap = &As[wr * 64 + ti * 16 + l15][lq * 8];
            f32x4 a0 = *(const f32x4*)(ap);
            f32x4 a1 = *(const f32x4*)(ap + 4);
#pragma unroll
            for (int j = 0; j < 4; ++j) {
                float x = a0[j];
                half_t h = (half_t)x;
                ah[ti][j] = h;
                al[ti][j] = (half_t)(x - (float)h);
            }
#pragma unroll
            for (int j = 0; j < 4; ++j) {
                float x = a1[j];
                half_t h = (half_t)x;
                ah[ti][4 + j] = h;
                al[ti][4 + j] = (half_t)(x - (float)h);
            }
        }

#pragma unroll
        for (int ti = 0; ti < 4; ++ti)
#pragma unroll
            for (int tj = 0; tj < 4; ++tj)
                acc[ti][tj] = __builtin_amdgcn_mfma_f32_16x16x32_f16(ah[ti], bh[tj], acc[ti][tj], 0, 0, 0);
#pragma unroll
        for (int ti = 0; ti < 4; ++ti)
#pragma unroll
            for (int tj = 0; tj < 4; ++tj)
                acc[ti][tj] = __builtin_amdgcn_mfma_f32_16x16x32_f16(ah[ti], bl[tj], acc[ti][tj], 0, 0, 0);
#pragma unroll
        for (int ti = 0; ti < 4; ++ti)
#pragma unroll
            for (int tj = 0; tj < 4; ++tj)
                acc[ti][tj] = __builtin_amdgcn_mfma_f32_16x16x32_f16(al[ti], bh[tj], acc[ti][tj], 0, 0, 0);
    }

    float* Cb = C + (size_t)(bm * 128 + wr * 64) * 768 + bn * 128 + wc * 64;
#pragma unroll
    for (int ti = 0; ti < 4; ++ti)
#pragma unroll
        for (int tj = 0; tj < 4; ++tj) {
            int r0 = ti * 16 + lq * 4;
            int c0 = tj * 16 + l15;
#pragma unroll
            for (int r = 0; r < 4; ++r)
                Cb[(size_t)(r0 + r) * 768 + c0] = acc[ti][tj][r];
        }
}

// ---------------------------------------------------------------------------
// Gate + pointer + memory update.  1 block/batch, 256 threads.
__global__ __launch_bounds__(256) void k_gate(const float* __restrict__ zf1,
                                              const float* __restrict__ ctrl_w,
                                              const float* __restrict__ ctrl_b,
                                              float* __restrict__ ptrv,
                                              float* __restrict__ memv) {
    __shared__ float zf[256];
    __shared__ float g[3];
    __shared__ float oldp[16];
    int b = blockIdx.x, tid = threadIdx.x;
    zf[tid] = zf1[b * FF + tid];
    if (tid < 16) oldp[tid] = ptrv[b * STK + tid];
    __syncthreads();
    int w = tid >> 6, lane = tid & 63;
    if (w < 3) {
        float s = 0.f;
#pragma unroll
        for (int q = 0; q < 4; ++q) {
            int c = lane + 64 * q;
            s += zf[c] * ctrl_w[c * 3 + w];
        }
#pragma unroll
        for (int off = 1; off < 64; off <<= 1) s += __shfl_xor(s, off);
        if (lane == 0) g[w] = 1.f / (1.f + expf(-(s + ctrl_b[w])));
    }
    __syncthreads();
    float tot = g[0] + g[1] + g[2] + 1e-6f;
    float push = g[0] / tot, pop = g[1] / tot, stay = g[2] / tot;
    if (tid < 16) {
        int s = tid;
        float np = push * oldp[(s + 15) & 15] + pop * oldp[(s + 1) & 15] + stay * oldp[s];
        ptrv[b * STK + s] = np;
    }
    for (int idx = tid; idx < STK * FF; idx += 256) {
        int c = idx & 255;
        size_t gi = (size_t)b * (STK * FF) + idx;
        float m = memv[gi];
        memv[gi] = m * (1.f - push) + push * zf[c];
    }
}

// ---------------------------------------------------------------------------
// Memory attention + pointer-weighted read.  1 block/batch, 256 threads.
__global__ __launch_bounds__(256) void k_memattn(const float* __restrict__ memqkv,
                                                 const float* __restrict__ ptrv,
                                                 float* __restrict__ readv) {
    __shared__ float mq[16][257];
    __shared__ float mk[16][257];
    __shared__ float mv[16][257];
    __shared__ float sm[16][17];
    __shared__ float rowmax[16], rowsum[16], pw[16];
    int b = blockIdx.x, tid = threadIdx.x;
    const float* mb = memqkv + (size_t)b * STK * 768;
    for (int idx = tid; idx < STK * FF; idx += 256) {
        int t = idx >> 8, c = idx & 255;
        mq[t][c] = mb[t * 768 + c];
        mk[t][c] = mb[t * 768 + 256 + c];
        mv[t][c] = mb[t * 768 + 512 + c];
    }
    __syncthreads();
    int i = tid >> 4, j = tid & 15;
    float s = 0.f;
#pragma unroll 8
    for (int c = 0; c < 256; ++c) s += mq[i][c] * mk[j][c];
    s *= 0.08838834764831845f;
    sm[i][j] = s;
    __syncthreads();
    if (tid < 16) {
        float m = -1e30f;
        for (int jj = 0; jj < 16; ++jj) m = fmaxf(m, sm[tid][jj]);
        float su = 0.f;
        for (int jj = 0; jj < 16; ++jj) su += expf(sm[tid][jj] - m);
        rowmax[tid] = m; rowsum[tid] = su;
    }
    __syncthreads();
    float p = expf(s - rowmax[i]) / rowsum[i];
    sm[i][j] = p;
    __syncthreads();
    if (tid < 16) {
        float a = 0.f;
        for (int ss2 = 0; ss2 < 16; ++ss2) a += ptrv[b * STK + ss2] * sm[ss2][tid];
        pw[tid] = a;
    }
    __syncthreads();
    {
        int c = tid;
        float a = 0.f;
#pragma unroll
        for (int jj = 0; jj < 16; ++jj) a += pw[jj] * mv[jj][c];
        readv[b * FF + c] = a;
    }
}

// ---------------------------------------------------------------------------
__device__ __forceinline__ float bredsum(float v, float* red, int n) {
    red[n] = v; __syncthreads();
    for (int off = 64; off > 0; off >>= 1) {
        if (n < off) red[n] += red[n + off];
        __syncthreads();
    }
    float r = red[0];
    __syncthreads();
    return r;
}
__device__ __forceinline__ float bredmax(float v, float* red, int n) {
    red[n] = v; __syncthreads();
    for (int off = 64; off > 0; off >>= 1) {
        if (n < off) red[n] = fmaxf(red[n], red[n + off]);
        __syncthreads();
    }
    float r = red[0];
    __syncthreads();
    return r;
}

// z += 0.1*read; zf2 = mean; mag partial sums; halting logit. 1 blk/batch, 128 thr.
__global__ __launch_bounds__(128) void k_zup2(float* __restrict__ z,
                                              const float* __restrict__ readv,
                                              float* __restrict__ zf2,
                                              const float* __restrict__ halt_w,
                                              const float* __restrict__ halt_b,
                                              float* __restrict__ pval,
                                              float* __restrict__ magpart) {
    __shared__ float red[128];
    int b = blockIdx.x, d = threadIdx.x;
    float rr = 0.1f * readv[b * FF + d];
    float ri = 0.1f * readv[b * FF + DD + d];
    float sr = 0.f, si = 0.f, ms = 0.f, msq = 0.f;
    float* zb = z + (size_t)b * (SS * FF);
    for (int s = 0; s < SS; ++s) {
        float zr = zb[s * FF + d] + rr;
        float zi = zb[s * FF + DD + d] + ri;
        zb[s * FF + d] = zr;
        zb[s * FF + DD + d] = zi;
        sr += zr; si += zi;
        float m2 = zr * zr + zi * zi;
        ms += sqrtf(m2); msq += m2;
    }
    float zfr = sr * (1.f / 64.f), zfi = si * (1.f / 64.f);
    zf2[b * FF + d] = zfr;
    zf2[b * FF + DD + d] = zfi;
    float tms = bredsum(ms, red, d);
    float tmsq = bredsum(msq, red, d);
    if (d == 0) { magpart[2 * b] = tms; magpart[2 * b + 1] = tmsq; }
    float hp = zfr * halt_w[d] + zfi * halt_w[DD + d];
    float thp = bredsum(hp, red, d);
    if (d == 0) pval[b] = 1.f / (1.f + expf(-(thp + halt_b[0])));
}

// VQ + ACT bookkeeping. 1 block/batch, 128 threads (one per symbol).
__global__ __launch_bounds__(128) void k_vq(const float* __restrict__ zf2,
                                            const float* __restrict__ cb,
                                            const float* __restrict__ cb2,
                                            const float* __restrict__ adj,
                                            float* __restrict__ probs,
                                            float* __restrict__ quant,
                                            float* __restrict__ halt,
                                            const float* __restrict__ pval,
                                            float* __restrict__ wact,
                                            const float* __restrict__ magpart, int t) {
    __shared__ float red[128];
    __shared__ float zf[256];
    __shared__ float pr[128];
    int b = blockIdx.x, n = threadIdx.x;
    zf[n] = zf2[b * FF + n];
    zf[DD + n] = zf2[b * FF + DD + n];
    float up = 0.f;
    if (t > 0) {
        float pa = 0.f, pb = 0.f;
        for (int k = n; k < BB; k += 128) { pa += magpart[2 * k]; pb += magpart[2 * k + 1]; }
        float tms = bredsum(pa, red, n);
        float tmsq = bredsum(pb, red, n);
        const float N = 4194304.f;   // B*S*D
        float mean = tms / N;
        float var = tmsq / N - mean * mean;
        float x = var / (1.f + 1e-6f);
        up = (x > 20.f) ? x : log1pf(expf(x));
    }
    __syncthreads();
    float part = zf[n] * zf[n] + zf[DD + n] * zf[DD + n];
    float zz = bredsum(part, red, n);
    float dot = 0.f;
    const float* cbn = cb + n * FF;
#pragma unroll 8
    for (int c = 0; c < FF; ++c) dot += zf[c] * cbn[c];
    float dist = (zz + cb2[n] - 2.f * dot) * (1.f / 256.f);
    float dtot = dist;
    if (t > 0) {
        float gb = 0.f;
        const float* pp = probs + b * NSYM;
        for (int k = 0; k < NSYM; ++k) gb += pp[k] * adj[k * NSYM + n];
        dtot = dist - 0.01f * up * (1.f / (1.f + expf(-gb)));
    }
    float v = -dtot;   // TEMP = 1
    float mx = bredmax(v, red, n);
    float e = expf(v - mx);
    float se = bredsum(e, red, n);
    float psm = e / se;
    pr[n] = psm;
    __syncthreads();
    probs[b * NSYM + n] = psm;
    float q0 = 0.f, q1 = 0.f;
    for (int k = 0; k < NSYM; ++k) {
        float pk = pr[k];
        q0 += pk * cb[k * FF + n];
        q1 += pk * cb[k * FF + DD + n];
    }
    quant[b * FF + n] = q0;
    quant[b * FF + DD + n] = q1;
    if (n == 0) {
        float h = halt[b], p = pval[b];
        float running = (h < 0.99f) ? 1.f : 0.f;
        float w = (((h + p * running) >= 0.99f) ? (1.f - h) : p) * running;
        halt[b] = h + w;
        wact[b] = w;
    }
}

// Apply last step's quant + ACT accumulation (deferred k_final for t = DEPTH-1).
__global__ __launch_bounds__(256) void k_epilogue(const float* __restrict__ z,
                                                  const float* __restrict__ quant,
                                                  const float* __restrict__ wact,
                                                  float* __restrict__ acc) {
    int idx = blockIdx.x * 256 + threadIdx.x;   // grid 32768 -> 8388608
    int b = idx >> 14;
    int c = idx & 255;
    float wa = wact[b];
    if (wa != 0.0f)
        acc[idx] += wa * (z[idx] + 0.1f * quant[b * FF + c]);
}

// ---------------------------------------------------------------------------
extern "C" void kernel_launch(void* const* d_in, const int* in_sizes, int n_in,
                              void* d_out, int out_size, void* d_ws, size_t ws_size,
                              hipStream_t stream) {
    const float* z_real  = (const float*)d_in[0];
    const float* z_imag  = (const float*)d_in[1];
    const float* attn_wr = (const float*)d_in[2];
    const float* attn_wi = (const float*)d_in[3];
    const float* mem_wr  = (const float*)d_in[4];
    const float* mem_wi  = (const float*)d_in[5];
    const float* ctrl_w  = (const float*)d_in[6];
    const float* ctrl_b  = (const float*)d_in[7];
    const float* halt_w  = (const float*)d_in[8];
    const float* halt_b  = (const float*)d_in[9];
    const float* codebook  = (const float*)d_in[10];
    const float* adjacency = (const float*)d_in[11];

    float* ws = (float*)d_ws;
    float* z      = ws + Z_OFF;
    float* WT32   = ws + QKV_OFF;
    half_t* GTh   = (half_t*)(ws + QKV_OFF + 196608);
    half_t* GTl   = GTh + 65536;
    half_t* WvTh  = GTl + 65536;
    half_t* WvTl  = WvTh + 65536;
    float* memv   = ws + MEM_OFF;
    float* memqkv = ws + MEMQKV_OFF;
    float* ptrv   = ws + PTR_OFF;
    float* zf1    = ws + ZF1_OFF;
    float* zf2    = ws + ZF2_OFF;
    float* readv  = ws + READ_OFF;
    float* probs  = ws + PROBS_OFF;
    float* quant  = ws + QUANT_OFF;
    float* halt   = ws + HALT_OFF;
    float* pval   = ws + PVAL_OFF;
    float* wact   = ws + WACT_OFF;
    float* magp   = ws + MAGP_OFF;
    half_t* WTh_m = (half_t*)(ws + MQKV_OFF);
    half_t* WTl_m = (half_t*)(ws + MQKV_OFF) + 196608;
    float* cb2    = ws + CB2_OFF;
    float* acc    = (float*)d_out;

    k_buildwt32<<<768, 256, 0, stream>>>(attn_wr, attn_wi, WT32);
    k_buildG<<<256, 256, 0, stream>>>(WT32, GTh, GTl);
    k_splitWv<<<256, 256, 0, stream>>>(WT32, WvTh, WvTl);
    k_buildwt<<<768, 256, 0, stream>>>(mem_wr, mem_wi, WTh_m, WTl_m);
    k_cb2<<<1, 128, 0, stream>>>(codebook, cb2);
    k_init<<<32768, 256, 0, stream>>>(z_real, z_imag, z, memv, ptrv, probs, halt, acc,
                                      quant, wact);

    for (int t = 0; t < NDEPTH; ++t) {
        k_attn_fused<<<BB, 256, 0, stream>>>(z, GTh, GTl, WvTh, WvTl, quant, wact, acc, zf1);
        k_gate<<<BB, 256, 0, stream>>>(zf1, ctrl_w, ctrl_b, ptrv, memv);
        gemm_split<<<(BB * STK / 128) * 6, 256, 0, stream>>>(memv, WTh_m, WTl_m, memqkv);
        k_memattn<<<BB, 256, 0, stream>>>(memqkv, ptrv, readv);
        k_zup2<<<BB, 128, 0, stream>>>(z, readv, zf2, halt_w, halt_b, pval, magp);
        k_vq<<<BB, 128, 0, stream>>>(zf2, codebook, cb2, adjacency, probs, quant,
                                     halt, pval, wact, magp, t);
    }
    k_epilogue<<<32768, 256, 0, stream>>>(z, quant, wact, acc);
}